// Round 5
// baseline (4389.763 us; speedup 1.0000x reference)
//
#include <hip/hip_runtime.h>
#include <hip/hip_bf16.h>
#include <math.h>

using bf16 = __hip_bfloat16;
typedef short bf16x8 __attribute__((ext_vector_type(8)));
typedef float f32x4 __attribute__((ext_vector_type(4)));

#define DEV __device__ __forceinline__

constexpr int BATCH = 2, SEQ = 4096, INPD = 1280, DM = 768, FFD = 3072;
constexpr int NL = 12, NH = 12, DHD = 64, NBLK = 64, NCLS = 2;
constexpr int MR = BATCH * SEQ;       // 8192 token rows
constexpr int QKVN = 3 * DM;          // 2304
constexpr int NJOBS = 62 + 16;        // interior blocks + 2 edges * 8 splits
constexpr int PARTF = 64 * 64 + 128;  // floats per edge partial (O + m + l)

DEV void gload_lds16(const void* g, void* l) {
  __builtin_amdgcn_global_load_lds(
      (const __attribute__((address_space(1))) unsigned int*)g,
      (__attribute__((address_space(3))) unsigned int*)l, 16, 0, 0);
}

DEV f32x4 mfma16(bf16x8 a, bf16x8 b, f32x4 c) {
  return __builtin_amdgcn_mfma_f32_16x16x32_bf16(a, b, c, 0, 0, 0);
}

// ----------------------------- f32 -> bf16 convert (16B stores) -----------------------------
__global__ void k_f32_to_bf16(const float* __restrict__ in, bf16* __restrict__ out, int n) {
  int i = (blockIdx.x * blockDim.x + threadIdx.x) * 8;
  int stride = gridDim.x * blockDim.x * 8;
  for (; i < n; i += stride) {
    float4 a = *(const float4*)(in + i);
    float4 b = *(const float4*)(in + i + 4);
    bf16 t8[8];
    t8[0] = __float2bfloat16(a.x); t8[1] = __float2bfloat16(a.y);
    t8[2] = __float2bfloat16(a.z); t8[3] = __float2bfloat16(a.w);
    t8[4] = __float2bfloat16(b.x); t8[5] = __float2bfloat16(b.y);
    t8[6] = __float2bfloat16(b.z); t8[7] = __float2bfloat16(b.w);
    *(bf16x8*)(out + i) = *(bf16x8*)t8;
  }
}

// ------------------------- weight transpose (K,N)f32 -> (N,K)bf16 -------------------------
DEV void tr32_tile(const float* __restrict__ src, bf16* __restrict__ dst,
                   int K, int N, int tile, float t[32][33], int tid) {
  int nt = N >> 5;
  int tk = tile / nt, tn = tile - tk * nt;
  int tx = tid & 31, ty = tid >> 5;
#pragma unroll
  for (int i = 0; i < 4; ++i)
    t[ty + 8 * i][tx] = src[(size_t)(tk * 32 + ty + 8 * i) * N + tn * 32 + tx];
  __syncthreads();
#pragma unroll
  for (int i = 0; i < 4; ++i)
    dst[(size_t)(tn * 32 + ty + 8 * i) * K + tk * 32 + tx] = __float2bfloat16(t[tx][ty + 8 * i]);
}

__global__ __launch_bounds__(256) void k_transpose_one(const float* __restrict__ src,
                                                       bf16* __restrict__ dst, int K, int N) {
  __shared__ float t[32][33];
  tr32_tile(src, dst, K, N, blockIdx.x, t, threadIdx.x);
}

__global__ __launch_bounds__(256) void k_transpose_layer(
    const float* __restrict__ Wq, const float* __restrict__ Wk,
    const float* __restrict__ Wv, const float* __restrict__ Wo,
    const float* __restrict__ W1, const float* __restrict__ W2,
    bf16* __restrict__ wqkvT, bf16* __restrict__ woT,
    bf16* __restrict__ w1T, bf16* __restrict__ w2T, int l) {
  __shared__ float t[32][33];
  int id = blockIdx.x;
  const float* src; bf16* dst; int K, N;
  if (id < 1728) {               // Wq,Wk,Wv -> concatenated (2304 x 768)
    int m = id / 576; id -= m * 576;
    src = (m == 0 ? Wq : m == 1 ? Wk : Wv) + (size_t)l * DM * DM;
    dst = wqkvT + (size_t)m * DM * DM; K = DM; N = DM;
  } else if (id < 2304) {
    id -= 1728; src = Wo + (size_t)l * DM * DM; dst = woT; K = DM; N = DM;
  } else if (id < 4608) {
    id -= 2304; src = W1 + (size_t)l * DM * FFD; dst = w1T; K = DM; N = FFD;
  } else {
    id -= 4608; src = W2 + (size_t)l * FFD * DM; dst = w2T; K = FFD; N = DM;
  }
  tr32_tile(src, dst, K, N, id, t, threadIdx.x);
}

// -------------------- 128^2 GEMM (2-phase, proven round-3): C = A * BT^T --------------------
// EPI: 0 = +segmented-bias(q/k/v) -> bf16 ; 1 = +bias, gelu -> bf16 ;
//      2 = +bias +res(f32) -> f32 ; 3 = +bias +pos_emb +tok_emb -> f32 (embed)
template <int EPI>
__global__ __launch_bounds__(256) void k_gemm(
    const bf16* __restrict__ A, const bf16* __restrict__ BT, int N, int K,
    const float* __restrict__ b0, const float* __restrict__ b1, const float* __restrict__ b2,
    const float* __restrict__ res, const float* __restrict__ pos, const float* __restrict__ tok,
    float* __restrict__ Cf, bf16* __restrict__ Cb) {
  __shared__ __align__(16) bf16 lA[2][128 * 32];
  __shared__ __align__(16) bf16 lB[2][128 * 32];
  const int tid = threadIdx.x;
  const int gx = gridDim.x;
  const int nwg = gx * gridDim.y;
  const int orig = blockIdx.y * gx + blockIdx.x;
  const int q = nwg >> 3, r = nwg & 7;
  const int xcd = orig & 7, pos_ = orig >> 3;
  const int tile = (xcd < r ? xcd * (q + 1) : r * (q + 1) + (xcd - r) * q) + pos_;
  const int bx = tile % gx, by = tile / gx;
  const int bm = by * 128, bn = bx * 128;
  const int lane = tid & 63, wid = tid >> 6;
  const int wm = (wid >> 1) * 64, wn = (wid & 1) * 64;
  const int lr = lane & 15, lks = lane >> 4;
  const bf16* Abase = A + (size_t)bm * K;
  const bf16* Bbase = BT + (size_t)bn * K;

  auto stage = [&](int buf, int t) {
    int k0 = t << 5;
#pragma unroll
    for (int ss = 0; ss < 2; ++ss) {
      int seg = tid + ss * 256;
      int row = seg >> 2, slot = seg & 3;
      int kseg = slot ^ ((row >> 1) & 3);
      gload_lds16(Abase + (size_t)row * K + k0 + kseg * 8, &lA[buf][seg * 8]);
      gload_lds16(Bbase + (size_t)row * K + k0 + kseg * 8, &lB[buf][seg * 8]);
    }
  };

  f32x4 acc[4][4] = {};
  const int nt = K >> 5;
  stage(0, 0);
  __syncthreads();
  for (int t = 0; t < nt; ++t) {
    const int buf = t & 1;
    if (t + 1 < nt) stage(buf ^ 1, t + 1);  // prefetch next tile under compute
    bf16x8 af[4], bfr[4];
#pragma unroll
    for (int m = 0; m < 4; ++m) {
      int rr = wm + m * 16 + lr;
      af[m] = *(const bf16x8*)(&lA[buf][rr * 32 + ((lks ^ ((rr >> 1) & 3)) << 3)]);
    }
#pragma unroll
    for (int n = 0; n < 4; ++n) {
      int rr = wn + n * 16 + lr;
      bfr[n] = *(const bf16x8*)(&lB[buf][rr * 32 + ((lks ^ ((rr >> 1) & 3)) << 3)]);
    }
#pragma unroll
    for (int m = 0; m < 4; ++m)
#pragma unroll
      for (int n = 0; n < 4; ++n)
        acc[m][n] = mfma16(af[m], bfr[n], acc[m][n]);
    __syncthreads();
  }
  const int gq = lane >> 4;
#pragma unroll
  for (int m = 0; m < 4; ++m) {
#pragma unroll
    for (int n = 0; n < 4; ++n) {
      int gcol = bn + wn + n * 16 + lr;
      f32x4 v = acc[m][n];
#pragma unroll
      for (int rr = 0; rr < 4; ++rr) {
        int grow = bm + wm + m * 16 + gq * 4 + rr;
        float x = v[rr];
        if constexpr (EPI == 0) {
          int c = gcol; const float* bb = b0;
          if (c >= 2 * DM) { bb = b2; c -= 2 * DM; }
          else if (c >= DM) { bb = b1; c -= DM; }
          x += bb[c];
          Cb[(size_t)grow * N + gcol] = __float2bfloat16(x);
        } else if constexpr (EPI == 1) {
          x += b0[gcol];
          x = 0.5f * x * (1.0f + erff(x * 0.70710678118654752f));
          Cb[(size_t)grow * N + gcol] = __float2bfloat16(x);
        } else if constexpr (EPI == 2) {
          x += b0[gcol] + res[(size_t)grow * N + gcol];
          Cf[(size_t)grow * N + gcol] = x;
        } else {
          x += b0[gcol] + pos[(size_t)(grow & (SEQ - 1)) * N + gcol] + tok[gcol];
          Cf[(size_t)grow * N + gcol] = x;
        }
      }
    }
  }
}

// ---------------- 256^2 8-phase GEMM (T2+T3+T4+T5), K=768 only, N%256==0 ----------------
// 8 waves (2M x 4N), per-wave 128x64 out; BK=64; LDS 128KB dbuf; rows 128B with
// slot^(row&7) swizzle (2-way max). Per iter: phases 1-4 compute buf0, 5-8 buf1;
// tile bursts at phase-1/5 tops into the freed buffer; vmcnt(0) only at phases 4/8
// (3 phases of MFMA cover). EPI: 0 = segmented qkv bias -> bf16; 1 = bias+gelu -> bf16.
template <int EPI>
__global__ __launch_bounds__(512, 2) void k_gemm256(
    const bf16* __restrict__ A, const bf16* __restrict__ BT, int N,
    const float* __restrict__ b0, const float* __restrict__ b1, const float* __restrict__ b2,
    bf16* __restrict__ Cb) {
  constexpr int K = 768;
  constexpr int nt = K / 64;  // 12 K-tiles, 6 iterations
  __shared__ __align__(16) bf16 lA[2][256 * 64];
  __shared__ __align__(16) bf16 lB[2][256 * 64];
  const int tid = threadIdx.x;
  const int gx = gridDim.x;
  const int nwg = gx * gridDim.y;
  const int orig = blockIdx.y * gx + blockIdx.x;
  const int q = nwg >> 3, r = nwg & 7;
  const int xcd = orig & 7, pos_ = orig >> 3;
  const int tile = (xcd < r ? xcd * (q + 1) : r * (q + 1) + (xcd - r) * q) + pos_;
  const int bx = tile % gx, by = tile / gx;
  const int bm = by * 256, bn = bx * 256;
  const int lane = tid & 63, wid = tid >> 6;
  const int wr = wid >> 2, wc = wid & 3;      // wave grid 2M x 4N
  const int lr = lane & 15, lks = lane >> 4;
  const bf16* Abase = A + (size_t)bm * K;
  const bf16* Bbase = BT + (size_t)bn * K;

  // burst-stage one 256x64 K-tile of A and B (8 gloads/thread); dest linear,
  // source k-slot pre-swizzled (slot ^= row&7) to match swizzled ds_read.
  auto stage_tile = [&](int buf, int kt) {
    const int k0 = kt * 64;
#pragma unroll
    for (int p = 0; p < 4; ++p) {
      int seg = tid + p * 512;            // 2048 segs = 256 rows x 8 slots
      int row = seg >> 3, slot = seg & 7;
      int kseg = slot ^ (row & 7);
      gload_lds16(Abase + (size_t)row * K + k0 + kseg * 8, &lA[buf][seg * 8]);
      gload_lds16(Bbase + (size_t)row * K + k0 + kseg * 8, &lB[buf][seg * 8]);
    }
  };

  f32x4 acc[8][4] = {};
  bf16x8 bfr[4];

  auto lda = [&](int buf, int m, int kk) {
    int rr = wr * 128 + m * 16 + lr;
    return *(const bf16x8*)(&lA[buf][rr * 64 + (((kk * 4 + lks) ^ (rr & 7)) << 3)]);
  };
  auto ldb = [&](int buf, int n, int kk) {
    int rr = wc * 64 + n * 16 + lr;
    return *(const bf16x8*)(&lB[buf][rr * 64 + (((kk * 4 + lks) ^ (rr & 7)) << 3)]);
  };

  // one phase: ds_read frags; optional vmcnt(0); barrier; lgkm0; 16 MFMA; barrier
  auto phase = [&](int buf, int kk, int mh, bool vmwait) {
    if (mh == 0) {
#pragma unroll
      for (int n = 0; n < 4; ++n) bfr[n] = ldb(buf, n, kk);
    }
    bf16x8 a0 = lda(buf, mh * 4 + 0, kk);
    bf16x8 a1 = lda(buf, mh * 4 + 1, kk);
    bf16x8 a2 = lda(buf, mh * 4 + 2, kk);
    bf16x8 a3 = lda(buf, mh * 4 + 3, kk);
    if (vmwait) {
      __builtin_amdgcn_sched_barrier(0);
      asm volatile("s_waitcnt vmcnt(0)" ::: "memory");
    }
    __builtin_amdgcn_s_barrier();
    asm volatile("s_waitcnt lgkmcnt(0)" ::: "memory");
    __builtin_amdgcn_sched_barrier(0);
    __builtin_amdgcn_s_setprio(1);
#pragma unroll
    for (int n = 0; n < 4; ++n) {
      acc[mh * 4 + 0][n] = mfma16(a0, bfr[n], acc[mh * 4 + 0][n]);
      acc[mh * 4 + 1][n] = mfma16(a1, bfr[n], acc[mh * 4 + 1][n]);
      acc[mh * 4 + 2][n] = mfma16(a2, bfr[n], acc[mh * 4 + 2][n]);
      acc[mh * 4 + 3][n] = mfma16(a3, bfr[n], acc[mh * 4 + 3][n]);
    }
    __builtin_amdgcn_s_setprio(0);
    __builtin_amdgcn_s_barrier();
  };

  stage_tile(0, 0);
  stage_tile(1, 1);
  __builtin_amdgcn_sched_barrier(0);
  asm volatile("s_waitcnt vmcnt(8)" ::: "memory");  // tile 0's 8 loads retired
  __builtin_amdgcn_s_barrier();

  for (int t = 0; t < nt / 2; ++t) {
    // half A: compute tile 2t (buf0); stage tile 2t+1 -> buf1 (freed end of prev P8)
    if (t > 0) stage_tile(1, 2 * t + 1);
    phase(0, 0, 0, false);
    phase(0, 0, 1, false);
    phase(0, 1, 0, false);
    phase(0, 1, 1, true);   // vmcnt(0): buf1's tile visible after this barrier
    // half B: compute tile 2t+1 (buf1); stage tile 2t+2 -> buf0 (freed at P4)
    if (2 * t + 2 < nt) stage_tile(0, 2 * t + 2);
    phase(1, 0, 0, false);
    phase(1, 0, 1, false);
    phase(1, 1, 0, false);
    phase(1, 1, 1, t + 1 < nt / 2);  // last iter: nothing in flight, skip wait
  }

  const int gq = lane >> 4;
#pragma unroll
  for (int m = 0; m < 8; ++m) {
#pragma unroll
    for (int n = 0; n < 4; ++n) {
      int gcol = bn + wc * 64 + n * 16 + lr;
      f32x4 v = acc[m][n];
#pragma unroll
      for (int rr = 0; rr < 4; ++rr) {
        int grow = bm + wr * 128 + m * 16 + gq * 4 + rr;
        float x = v[rr];
        if constexpr (EPI == 0) {
          int c = gcol; const float* bb = b0;
          if (c >= 2 * DM) { bb = b2; c -= 2 * DM; }
          else if (c >= DM) { bb = b1; c -= DM; }
          x += bb[c];
        } else {
          x += b0[gcol];
          x = 0.5f * x * (1.0f + erff(x * 0.70710678118654752f));
        }
        Cb[(size_t)grow * N + gcol] = __float2bfloat16(x);
      }
    }
  }
}

// --------------- LayerNorm: wave-per-row, float4 loads, shuffle-only reduce ---------------
typedef short bf16x4v __attribute__((ext_vector_type(4)));
__global__ __launch_bounds__(256) void k_ln(const float* __restrict__ in,
                                            const float* __restrict__ g, const float* __restrict__ b,
                                            float* __restrict__ xf, bf16* __restrict__ xb) {
  const int wv = threadIdx.x >> 6, lane = threadIdx.x & 63;
  const int row = blockIdx.x * 4 + wv;
  const float4* rp = (const float4*)(in + (size_t)row * DM);
  float4 v[3];
  float s = 0.f, s2 = 0.f;
#pragma unroll
  for (int i = 0; i < 3; ++i) {
    float4 t = rp[i * 64 + lane];
    v[i] = t;
    s += t.x + t.y + t.z + t.w;
    s2 += t.x * t.x + t.y * t.y + t.z * t.z + t.w * t.w;
  }
#pragma unroll
  for (int off = 1; off < 64; off <<= 1) {
    s += __shfl_xor(s, off);
    s2 += __shfl_xor(s2, off);
  }
  const float mean = s * (1.0f / DM);
  const float var = s2 * (1.0f / DM) - mean * mean;
  const float rs = rsqrtf(var + 1e-12f);
  float4* xfp = (float4*)(xf + (size_t)row * DM);
  bf16* xbp = xb + (size_t)row * DM;
#pragma unroll
  for (int i = 0; i < 3; ++i) {
    const int c4 = i * 64 + lane;
    float4 g4 = ((const float4*)g)[c4];
    float4 b4 = ((const float4*)b)[c4];
    float4 y;
    y.x = (v[i].x - mean) * rs * g4.x + b4.x;
    y.y = (v[i].y - mean) * rs * g4.y + b4.y;
    y.z = (v[i].z - mean) * rs * g4.z + b4.z;
    y.w = (v[i].w - mean) * rs * g4.w + b4.w;
    xfp[c4] = y;
    bf16 t4[4];
    t4[0] = __float2bfloat16(y.x); t4[1] = __float2bfloat16(y.y);
    t4[2] = __float2bfloat16(y.z); t4[3] = __float2bfloat16(y.w);
    *(bf16x4v*)(xbp + c4 * 4) = *(bf16x4v*)t4;
  }
}

// ------------------- V transpose: qkv v-section (B,S,H,DH) -> vt (B,H,DH,S) -------------------
__global__ __launch_bounds__(256) void k_vt(const bf16* __restrict__ qkv, bf16* __restrict__ vt) {
  __shared__ unsigned short t[64][72];
  const int bh = blockIdx.y, t0 = blockIdx.x * 64;
  const int b = bh / NH, h = bh - b * NH;
  const int tid = threadIdx.x;
  const int rr = tid >> 2, cs = (tid & 3) * 16;
  const unsigned short* src = (const unsigned short*)qkv +
      (size_t)(b * SEQ + t0 + rr) * QKVN + 2 * DM + h * DHD + cs;
#pragma unroll
  for (int i = 0; i < 16; ++i) t[cs + i][rr] = src[i];
  __syncthreads();
  unsigned short* dst = (unsigned short*)vt + (size_t)(bh * DHD + rr) * SEQ + t0 + cs;
#pragma unroll
  for (int i = 0; i < 16; ++i) dst[i] = t[rr][cs + i];
}

// ----------------------------- block-sparse attention -----------------------------
__global__ __launch_bounds__(256) void k_attn(
    const bf16* __restrict__ qkv, const bf16* __restrict__ vt,
    const int* __restrict__ blk_idx,
    bf16* __restrict__ ctx, float* __restrict__ epart) {
  __shared__ __align__(16) bf16 sQ[64 * 64];
  __shared__ __align__(16) bf16 sK[2][64 * 64];
  __shared__ __align__(16) bf16 sV[2][64 * 64];
  __shared__ __align__(16) bf16 sP[4][16 * 64];
  const int job = blockIdx.x;
  const int b = job / (NH * NJOBS);
  const int rem = job - b * NH * NJOBS;
  const int h = rem / NJOBS;
  const int j = rem - h * NJOBS;
  const int tid = threadIdx.x, lane = tid & 63, w = tid >> 6;
  const int lr = lane & 15, lks = lane >> 4;

  const bool interior = (j < 62);
  int qblk, e = 0, split = 0;
  if (interior) qblk = j + 1;
  else { int tt = j - 62; e = tt >> 3; split = tt & 7; qblk = e ? NBLK - 1 : 0; }
  const int qt0 = qblk * 64;

  const int skip_pos = interior ? (j == 0 ? 2 : (j == 61 ? 4 : 8)) : 8;
  const int nkb = (skip_pos < 8) ? 7 : 8;
  auto kbi_of = [&](int i) {
    int kb = i + (i >= skip_pos ? 1 : 0);
    return interior ? blk_idx[j * 8 + kb] : split * 8 + kb;
  };

  const bf16* kbase0 = qkv + (size_t)b * SEQ * QKVN + DM + h * DHD;
  const bf16* vbase0 = vt + (size_t)((b * NH + h) * DHD) * SEQ;
  auto stageKV = [&](int buf, int kbi) {
    const int kt0 = kbi * 64;
#pragma unroll
    for (int ss = 0; ss < 2; ++ss) {
      int seg = tid + ss * 256;
      int row = seg >> 3, slot = seg & 7;
      int kseg = slot ^ (row & 7);
      gload_lds16(kbase0 + (size_t)(kt0 + row) * QKVN + kseg * 8, &sK[buf][seg * 8]);
      gload_lds16(vbase0 + (size_t)row * SEQ + kt0 + kseg * 8, &sV[buf][seg * 8]);
    }
  };

  {
    const bf16* qbase = qkv + (size_t)(b * SEQ + qt0) * QKVN + h * DHD;
#pragma unroll
    for (int ss = 0; ss < 2; ++ss) {
      int seg = tid + ss * 256;
      int row = seg >> 3, slot = seg & 7;
      int kseg = slot ^ (row & 7);
      gload_lds16(qbase + (size_t)row * QKVN + kseg * 8, sQ + seg * 8);
    }
  }
  stageKV(0, kbi_of(0));
  __syncthreads();
  bf16x8 aq[2];
#pragma unroll
  for (int kk = 0; kk < 2; ++kk) {
    int rq = w * 16 + lr;
    int slot = (kk * 4 + lks) ^ (rq & 7);
    aq[kk] = *(const bf16x8*)(sQ + rq * 64 + slot * 8);
  }

  float m_r[4], l_r[4];
  f32x4 o[4] = {};
#pragma unroll
  for (int r = 0; r < 4; ++r) { m_r[r] = -1e30f; l_r[r] = 0.f; }

  for (int i = 0; i < nkb; ++i) {
    const int buf = i & 1;
    if (i + 1 < nkb) stageKV(buf ^ 1, kbi_of(i + 1));
    f32x4 sfr[4];
#pragma unroll
    for (int n = 0; n < 4; ++n) {
      f32x4 z = {};
#pragma unroll
      for (int kk = 0; kk < 2; ++kk) {
        int rk = n * 16 + lr;
        int slot = (kk * 4 + lks) ^ (rk & 7);
        bf16x8 kf = *(const bf16x8*)(&sK[buf][rk * 64 + slot * 8]);
        z = mfma16(aq[kk], kf, z);
      }
      sfr[n] = z;
    }
#pragma unroll
    for (int n = 0; n < 4; ++n)
#pragma unroll
      for (int r = 0; r < 4; ++r) sfr[n][r] *= 0.125f;
    float alpha[4];
#pragma unroll
    for (int r = 0; r < 4; ++r) {
      float tmx = fmaxf(fmaxf(sfr[0][r], sfr[1][r]), fmaxf(sfr[2][r], sfr[3][r]));
#pragma unroll
      for (int off = 1; off < 16; off <<= 1) tmx = fmaxf(tmx, __shfl_xor(tmx, off));
      float mnew = fmaxf(m_r[r], tmx);
      alpha[r] = __expf(m_r[r] - mnew);
      m_r[r] = mnew;
    }
#pragma unroll
    for (int r = 0; r < 4; ++r) {
      float su = 0.f;
#pragma unroll
      for (int n = 0; n < 4; ++n) {
        float p = __expf(sfr[n][r] - m_r[r]);
        sfr[n][r] = p;
        su += p;
      }
#pragma unroll
      for (int off = 1; off < 16; off <<= 1) su += __shfl_xor(su, off);
      l_r[r] = l_r[r] * alpha[r] + su;
    }
#pragma unroll
    for (int n = 0; n < 4; ++n) {
#pragma unroll
      for (int r = 0; r < 4; ++r) {
        int prow = lks * 4 + r;
        int col = n * 16 + lr;
        int eo = prow * 64 + ((((col >> 3) ^ (prow & 7)) << 3) | (col & 7));
        sP[w][eo] = __float2bfloat16(sfr[n][r]);
      }
    }
#pragma unroll
    for (int n = 0; n < 4; ++n)
#pragma unroll
      for (int r = 0; r < 4; ++r) o[n][r] *= alpha[r];
    asm volatile("s_waitcnt lgkmcnt(0)" ::: "memory");
    __builtin_amdgcn_sched_barrier(0);
    bf16x8 pa[2];
#pragma unroll
    for (int kk = 0; kk < 2; ++kk) {
      int slot = (kk * 4 + lks) ^ (lr & 7);
      pa[kk] = *(const bf16x8*)(sP[w] + lr * 64 + slot * 8);
    }
#pragma unroll
    for (int n = 0; n < 4; ++n) {
#pragma unroll
      for (int kk = 0; kk < 2; ++kk) {
        int rv = n * 16 + lr;
        int slot = (kk * 4 + lks) ^ (rv & 7);
        bf16x8 vf = *(const bf16x8*)(&sV[buf][rv * 64 + slot * 8]);
        o[n] = mfma16(pa[kk], vf, o[n]);
      }
    }
    __syncthreads();
  }
  if (interior) {
#pragma unroll
    for (int r = 0; r < 4; ++r) {
      float inv = 1.0f / l_r[r];
      int tok = qt0 + w * 16 + lks * 4 + r;
#pragma unroll
      for (int n = 0; n < 4; ++n) {
        int col = h * DHD + n * 16 + lr;
        ctx[(size_t)(b * SEQ + tok) * DM + col] = __float2bfloat16(o[n][r] * inv);
      }
    }
  } else {
    float* base = epart + (size_t)((((b * NH + h) * 2 + e) * 8) + split) * PARTF;
#pragma unroll
    for (int r = 0; r < 4; ++r) {
      int qrow = w * 16 + lks * 4 + r;
#pragma unroll
      for (int n = 0; n < 4; ++n)
        base[qrow * 64 + n * 16 + lr] = o[n][r];
      if (lr == 0) { base[4096 + qrow] = m_r[r]; base[4096 + 64 + qrow] = l_r[r]; }
    }
  }
}

// ----------------------------- edge split-K combine -----------------------------
__global__ __launch_bounds__(256) void k_combine(const float* __restrict__ epart,
                                                 bf16* __restrict__ ctx) {
  const int bid = blockIdx.x;
  const int b = bid / (NH * 2);
  const int rem = bid - b * NH * 2;
  const int h = rem >> 1, e = rem & 1;
  const int tid = threadIdx.x;
  const int row = tid >> 2, cq = tid & 3;
  const float* base0 = epart + (size_t)(((b * NH + h) * 2 + e) * 8) * PARTF;
  float ms[8], ls[8], M = -1e30f;
#pragma unroll
  for (int s = 0; s < 8; ++s) {
    const float* bp = base0 + (size_t)s * PARTF;
    ms[s] = bp[4096 + row];
    ls[s] = bp[4096 + 64 + row];
    M = fmaxf(M, ms[s]);
  }
  float Lt = 0.f, accv[16];
#pragma unroll
  for (int i = 0; i < 16; ++i) accv[i] = 0.f;
#pragma unroll
  for (int s = 0; s < 8; ++s) {
    float wgt = __expf(ms[s] - M);
    Lt += ls[s] * wgt;
    const float* op = base0 + (size_t)s * PARTF + row * 64 + cq * 16;
#pragma unroll
    for (int i = 0; i < 16; ++i) accv[i] += op[i] * wgt;
  }
  float inv = 1.0f / Lt;
  int qblk = e ? NBLK - 1 : 0;
  int tok = qblk * 64 + row;
  bf16* cp = ctx + (size_t)(b * SEQ + tok) * DM + h * DHD + cq * 16;
#pragma unroll
  for (int i = 0; i < 16; ++i) cp[i] = __float2bfloat16(accv[i] * inv);
}

// ----------------------------- classifier: x[:,0,:] @ Wc + bc -----------------------------
__global__ void k_classifier(const float* __restrict__ xf, const float* __restrict__ Wc,
                             const float* __restrict__ bc, float* __restrict__ out) {
  const int tid = threadIdx.x, lane = tid & 63, wv = tid >> 6;
  const int b = wv >> 1, c = wv & 1;
  float s = 0.f;
  for (int d = lane; d < DM; d += 64)
    s += xf[(size_t)(b * SEQ) * DM + d] * Wc[d * NCLS + c];
#pragma unroll
  for (int off = 32; off > 0; off >>= 1) s += __shfl_down(s, off);
  if (lane == 0) out[b * NCLS + c] = s + bc[c];
}

// ----------------------------- host launch -----------------------------
extern "C" void kernel_launch(void* const* d_in, const int* in_sizes, int n_in,
                              void* d_out, int out_size, void* d_ws, size_t ws_size,
                              hipStream_t stream) {
  const float* embeddings = (const float*)d_in[0];
  const float* Wp  = (const float*)d_in[2];
  const float* bp  = (const float*)d_in[3];
  const float* pos = (const float*)d_in[4];
  const float* tokv = (const float*)d_in[5];
  const float* lng = (const float*)d_in[6];
  const float* lnb = (const float*)d_in[7];
  const float* Wq  = (const float*)d_in[8];
  const float* bq  = (const float*)d_in[9];
  const float* Wk  = (const float*)d_in[10];
  const float* bk  = (const float*)d_in[11];
  const float* Wv  = (const float*)d_in[12];
  const float* bv  = (const float*)d_in[13];
  const float* Wo  = (const float*)d_in[14];
  const float* bo  = (const float*)d_in[15];
  const float* l1g = (const float*)d_in[16];
  const float* l1b = (const float*)d_in[17];
  const float* W1  = (const float*)d_in[18];
  const float* b1  = (const float*)d_in[19];
  const float* W2  = (const float*)d_in[20];
  const float* b2  = (const float*)d_in[21];
  const float* l2g = (const float*)d_in[22];
  const float* l2b = (const float*)d_in[23];
  const float* Wc  = (const float*)d_in[24];
  const float* bc  = (const float*)d_in[25];
  const int*  bidx = (const int*)d_in[26];
  (void)in_sizes; (void)n_in; (void)out_size; (void)ws_size;

  char* ws = (char*)d_ws;
  size_t off = 0;
  auto alloc = [&](size_t bytes) -> char* {
    char* p = ws + off;
    off += (bytes + 255) & ~(size_t)255;
    return p;
  };
  bf16*  embB  = (bf16*)alloc((size_t)MR * INPD * 2);
  bf16*  wpT   = (bf16*)alloc((size_t)DM * INPD * 2);
  bf16*  wqkvT = (bf16*)alloc((size_t)QKVN * DM * 2);
  bf16*  woT   = (bf16*)alloc((size_t)DM * DM * 2);
  bf16*  w1T   = (bf16*)alloc((size_t)FFD * DM * 2);
  bf16*  w2T   = (bf16*)alloc((size_t)DM * FFD * 2);
  float* xf    = (float*)alloc((size_t)MR * DM * 4);
  bf16*  xb    = (bf16*)alloc((size_t)MR * DM * 2);
  float* preLN = (float*)alloc((size_t)MR * DM * 4);
  bf16*  qkvB  = (bf16*)alloc((size_t)MR * QKVN * 2);
  bf16*  vtB   = (bf16*)alloc((size_t)BATCH * NH * DHD * SEQ * 2);
  bf16*  ctxB  = (bf16*)alloc((size_t)MR * DM * 2);
  bf16*  hB    = (bf16*)alloc((size_t)MR * FFD * 2);
  float* epart = (float*)alloc((size_t)BATCH * NH * 2 * 8 * PARTF * 4);

  // embed: x = emb @ Wp + bp + pos + tok, then LN
  k_f32_to_bf16<<<2048, 256, 0, stream>>>(embeddings, embB, MR * INPD);
  k_transpose_one<<<(INPD / 32) * (DM / 32), 256, 0, stream>>>(Wp, wpT, INPD, DM);
  k_gemm<3><<<dim3(DM / 128, MR / 128), 256, 0, stream>>>(embB, wpT, DM, INPD,
      bp, nullptr, nullptr, nullptr, pos, tokv, preLN, nullptr);
  k_ln<<<MR / 4, 256, 0, stream>>>(preLN, lng, lnb, xf, xb);

  for (int l = 0; l < NL; ++l) {
    k_transpose_layer<<<6912, 256, 0, stream>>>(Wq, Wk, Wv, Wo, W1, W2,
        wqkvT, woT, w1T, w2T, l);
    k_gemm256<0><<<dim3(QKVN / 256, MR / 256), 512, 0, stream>>>(xb, wqkvT, QKVN,
        bq + (size_t)l * DM, bk + (size_t)l * DM, bv + (size_t)l * DM, qkvB);
    k_vt<<<dim3(SEQ / 64, BATCH * NH), 256, 0, stream>>>(qkvB, vtB);
    k_attn<<<BATCH * NH * NJOBS, 256, 0, stream>>>(qkvB, vtB, bidx, ctxB, epart);
    k_combine<<<BATCH * NH * 2, 256, 0, stream>>>(epart, ctxB);
    k_gemm<2><<<dim3(DM / 128, MR / 128), 256, 0, stream>>>(ctxB, woT, DM, DM,
        bo + (size_t)l * DM, nullptr, nullptr, xf, nullptr, nullptr, preLN, nullptr);
    k_ln<<<MR / 4, 256, 0, stream>>>(preLN, l1g + (size_t)l * DM, l1b + (size_t)l * DM, xf, xb);
    k_gemm256<1><<<dim3(FFD / 256, MR / 256), 512, 0, stream>>>(xb, w1T, FFD,
        b1 + (size_t)l * FFD, nullptr, nullptr, hB);
    k_gemm<2><<<dim3(DM / 128, MR / 128), 256, 0, stream>>>(hB, w2T, DM, FFD,
        b2 + (size_t)l * DM, nullptr, nullptr, xf, nullptr, nullptr, preLN, nullptr);
    k_ln<<<MR / 4, 256, 0, stream>>>(preLN, l2g + (size_t)l * DM, l2b + (size_t)l * DM, xf, xb);
  }
  k_classifier<<<1, 256, 0, stream>>>(xf, Wc, bc, (float*)d_out);
}

// Round 6
// 3724.460 us; speedup vs baseline: 1.1786x; 1.1786x over previous
//
#include <hip/hip_runtime.h>
#include <hip/hip_bf16.h>
#include <math.h>

using bf16 = __hip_bfloat16;
typedef short bf16x8 __attribute__((ext_vector_type(8)));
typedef float f32x4 __attribute__((ext_vector_type(4)));

#define DEV __device__ __forceinline__

constexpr int BATCH = 2, SEQ = 4096, INPD = 1280, DM = 768, FFD = 3072;
constexpr int NL = 12, NH = 12, DHD = 64, NBLK = 64, NCLS = 2;
constexpr int MR = BATCH * SEQ;       // 8192 token rows
constexpr int QKVN = 3 * DM;          // 2304
constexpr int NJOBS = 62 + 16;        // interior blocks + 2 edges * 8 splits
constexpr int PARTF = 64 * 64 + 128;  // floats per edge partial (O + m + l)

DEV void gload_lds16(const void* g, void* l) {
  __builtin_amdgcn_global_load_lds(
      (const __attribute__((address_space(1))) unsigned int*)g,
      (__attribute__((address_space(3))) unsigned int*)l, 16, 0, 0);
}

DEV f32x4 mfma16(bf16x8 a, bf16x8 b, f32x4 c) {
  return __builtin_amdgcn_mfma_f32_16x16x32_bf16(a, b, c, 0, 0, 0);
}

// XCD-chunked bijective block swizzle (m204): nwg must be tracked by caller grids.
DEV int xcd_swizzle(int orig, int nwg) {
  int q = nwg >> 3, r = nwg & 7;
  int xcd = orig & 7, pos_ = orig >> 3;
  return (xcd < r ? xcd * (q + 1) : r * (q + 1) + (xcd - r) * q) + pos_;
}

// ----------------------------- f32 -> bf16 convert (16B stores) -----------------------------
__global__ void k_f32_to_bf16(const float* __restrict__ in, bf16* __restrict__ out, int n) {
  int i = (blockIdx.x * blockDim.x + threadIdx.x) * 8;
  int stride = gridDim.x * blockDim.x * 8;
  for (; i < n; i += stride) {
    float4 a = *(const float4*)(in + i);
    float4 b = *(const float4*)(in + i + 4);
    bf16 t8[8];
    t8[0] = __float2bfloat16(a.x); t8[1] = __float2bfloat16(a.y);
    t8[2] = __float2bfloat16(a.z); t8[3] = __float2bfloat16(a.w);
    t8[4] = __float2bfloat16(b.x); t8[5] = __float2bfloat16(b.y);
    t8[6] = __float2bfloat16(b.z); t8[7] = __float2bfloat16(b.w);
    *(bf16x8*)(out + i) = *(bf16x8*)t8;
  }
}

// ------------------------- weight transpose (K,N)f32 -> (N,K)bf16 -------------------------
DEV void tr32_tile(const float* __restrict__ src, bf16* __restrict__ dst,
                   int K, int N, int tile, float t[32][33], int tid) {
  int nt = N >> 5;
  int tk = tile / nt, tn = tile - tk * nt;
  int tx = tid & 31, ty = tid >> 5;
#pragma unroll
  for (int i = 0; i < 4; ++i)
    t[ty + 8 * i][tx] = src[(size_t)(tk * 32 + ty + 8 * i) * N + tn * 32 + tx];
  __syncthreads();
#pragma unroll
  for (int i = 0; i < 4; ++i)
    dst[(size_t)(tn * 32 + ty + 8 * i) * K + tk * 32 + tx] = __float2bfloat16(t[tx][ty + 8 * i]);
}

__global__ __launch_bounds__(256) void k_transpose_one(const float* __restrict__ src,
                                                       bf16* __restrict__ dst, int K, int N) {
  __shared__ float t[32][33];
  tr32_tile(src, dst, K, N, blockIdx.x, t, threadIdx.x);
}

__global__ __launch_bounds__(256) void k_transpose_layer(
    const float* __restrict__ Wq, const float* __restrict__ Wk,
    const float* __restrict__ Wv, const float* __restrict__ Wo,
    const float* __restrict__ W1, const float* __restrict__ W2,
    bf16* __restrict__ wqkvT, bf16* __restrict__ woT,
    bf16* __restrict__ w1T, bf16* __restrict__ w2T, int l) {
  __shared__ float t[32][33];
  int id = blockIdx.x;
  const float* src; bf16* dst; int K, N;
  if (id < 1728) {               // Wq,Wk,Wv -> concatenated (2304 x 768)
    int m = id / 576; id -= m * 576;
    src = (m == 0 ? Wq : m == 1 ? Wk : Wv) + (size_t)l * DM * DM;
    dst = wqkvT + (size_t)m * DM * DM; K = DM; N = DM;
  } else if (id < 2304) {
    id -= 1728; src = Wo + (size_t)l * DM * DM; dst = woT; K = DM; N = DM;
  } else if (id < 4608) {
    id -= 2304; src = W1 + (size_t)l * DM * FFD; dst = w1T; K = DM; N = FFD;
  } else {
    id -= 4608; src = W2 + (size_t)l * FFD * DM; dst = w2T; K = FFD; N = DM;
  }
  tr32_tile(src, dst, K, N, id, t, threadIdx.x);
}

// -------------------- 128^2 GEMM (2-phase, proven round-3): C = A * BT^T --------------------
// For wide-N GEMMs (QKV N=2304, W1 N=3072) where the grid fills the chip.
// EPI: 0 = +segmented-bias(q/k/v) -> bf16 ; 1 = +bias, gelu -> bf16
template <int EPI>
__global__ __launch_bounds__(256) void k_gemm(
    const bf16* __restrict__ A, const bf16* __restrict__ BT, int N, int K,
    const float* __restrict__ b0, const float* __restrict__ b1, const float* __restrict__ b2,
    bf16* __restrict__ Cb) {
  __shared__ __align__(16) bf16 lA[2][128 * 32];
  __shared__ __align__(16) bf16 lB[2][128 * 32];
  const int tid = threadIdx.x;
  const int gx = gridDim.x;
  const int tile = xcd_swizzle(blockIdx.y * gx + blockIdx.x, gx * gridDim.y);
  const int bx = tile % gx, by = tile / gx;
  const int bm = by * 128, bn = bx * 128;
  const int lane = tid & 63, wid = tid >> 6;
  const int wm = (wid >> 1) * 64, wn = (wid & 1) * 64;
  const int lr = lane & 15, lks = lane >> 4;
  const bf16* Abase = A + (size_t)bm * K;
  const bf16* Bbase = BT + (size_t)bn * K;

  // stage 128x32 tiles; dest linear (gload_lds), source slot pre-swizzled
  // (slot ^= (row>>1)&3) so swizzled ds_read_b128 is 2-way max (free, m136).
  auto stage = [&](int buf, int t) {
    int k0 = t << 5;
#pragma unroll
    for (int ss = 0; ss < 2; ++ss) {
      int seg = tid + ss * 256;
      int row = seg >> 2, slot = seg & 3;
      int kseg = slot ^ ((row >> 1) & 3);
      gload_lds16(Abase + (size_t)row * K + k0 + kseg * 8, &lA[buf][seg * 8]);
      gload_lds16(Bbase + (size_t)row * K + k0 + kseg * 8, &lB[buf][seg * 8]);
    }
  };

  f32x4 acc[4][4] = {};
  const int nt = K >> 5;
  stage(0, 0);
  __syncthreads();
  for (int t = 0; t < nt; ++t) {
    const int buf = t & 1;
    if (t + 1 < nt) stage(buf ^ 1, t + 1);  // prefetch next tile under compute
    bf16x8 af[4], bfr[4];
#pragma unroll
    for (int m = 0; m < 4; ++m) {
      int rr = wm + m * 16 + lr;
      af[m] = *(const bf16x8*)(&lA[buf][rr * 32 + ((lks ^ ((rr >> 1) & 3)) << 3)]);
    }
#pragma unroll
    for (int n = 0; n < 4; ++n) {
      int rr = wn + n * 16 + lr;
      bfr[n] = *(const bf16x8*)(&lB[buf][rr * 32 + ((lks ^ ((rr >> 1) & 3)) << 3)]);
    }
#pragma unroll
    for (int m = 0; m < 4; ++m)
#pragma unroll
      for (int n = 0; n < 4; ++n)
        acc[m][n] = mfma16(af[m], bfr[n], acc[m][n]);
    __syncthreads();
  }
  const int gq = lane >> 4;
#pragma unroll
  for (int m = 0; m < 4; ++m) {
#pragma unroll
    for (int n = 0; n < 4; ++n) {
      int gcol = bn + wn + n * 16 + lr;
      f32x4 v = acc[m][n];
#pragma unroll
      for (int rr = 0; rr < 4; ++rr) {
        int grow = bm + wm + m * 16 + gq * 4 + rr;
        float x = v[rr];
        if constexpr (EPI == 0) {
          int c = gcol; const float* bb = b0;
          if (c >= 2 * DM) { bb = b2; c -= 2 * DM; }
          else if (c >= DM) { bb = b1; c -= DM; }
          x += bb[c];
        } else {
          x += b0[gcol];
          x = 0.5f * x * (1.0f + erff(x * 0.70710678118654752f));
        }
        Cb[(size_t)grow * N + gcol] = __float2bfloat16(x);
      }
    }
  }
}

// ---------------- 128x64 GEMM for N=768 (grid-starved shapes: W2, O-proj, embed) ----------------
// BM=128, BN=64, BK=32, 4 waves (2M x 2N), per-wave 64x32 out; LDS 24KB -> high occupancy;
// grid = (N/64) x (M/128) = 768 blocks = 3/CU. Same 2-phase skeleton as k_gemm.
// EPI: 2 = +bias +res(f32) -> f32 ; 3 = +bias +pos_emb +tok_emb -> f32 (embed)
template <int EPI>
__global__ __launch_bounds__(256) void k_gemm_n64(
    const bf16* __restrict__ A, const bf16* __restrict__ BT, int N, int K,
    const float* __restrict__ b0, const float* __restrict__ res,
    const float* __restrict__ pos, const float* __restrict__ tok,
    float* __restrict__ Cf) {
  __shared__ __align__(16) bf16 lA[2][128 * 32];
  __shared__ __align__(16) bf16 lB[2][64 * 32];
  const int tid = threadIdx.x;
  const int gx = gridDim.x;
  const int tile = xcd_swizzle(blockIdx.y * gx + blockIdx.x, gx * gridDim.y);
  const int bx = tile % gx, by = tile / gx;
  const int bm = by * 128, bn = bx * 64;
  const int lane = tid & 63, wid = tid >> 6;
  const int wm = (wid >> 1) * 64, wn = (wid & 1) * 32;
  const int lr = lane & 15, lks = lane >> 4;
  const bf16* Abase = A + (size_t)bm * K;
  const bf16* Bbase = BT + (size_t)bn * K;

  auto stage = [&](int buf, int t) {
    int k0 = t << 5;
#pragma unroll
    for (int ss = 0; ss < 2; ++ss) {  // A: 512 segs (128 rows x 4 slots)
      int seg = tid + ss * 256;
      int row = seg >> 2, slot = seg & 3;
      int kseg = slot ^ ((row >> 1) & 3);
      gload_lds16(Abase + (size_t)row * K + k0 + kseg * 8, &lA[buf][seg * 8]);
    }
    {  // B: 256 segs (64 rows x 4 slots)
      int row = tid >> 2, slot = tid & 3;
      int kseg = slot ^ ((row >> 1) & 3);
      gload_lds16(Bbase + (size_t)row * K + k0 + kseg * 8, &lB[buf][tid * 8]);
    }
  };

  f32x4 acc[4][2] = {};
  const int nt = K >> 5;
  stage(0, 0);
  __syncthreads();
  for (int t = 0; t < nt; ++t) {
    const int buf = t & 1;
    if (t + 1 < nt) stage(buf ^ 1, t + 1);
    bf16x8 af[4], bfr[2];
#pragma unroll
    for (int m = 0; m < 4; ++m) {
      int rr = wm + m * 16 + lr;
      af[m] = *(const bf16x8*)(&lA[buf][rr * 32 + ((lks ^ ((rr >> 1) & 3)) << 3)]);
    }
#pragma unroll
    for (int n = 0; n < 2; ++n) {
      int rr = wn + n * 16 + lr;
      bfr[n] = *(const bf16x8*)(&lB[buf][rr * 32 + ((lks ^ ((rr >> 1) & 3)) << 3)]);
    }
#pragma unroll
    for (int m = 0; m < 4; ++m)
#pragma unroll
      for (int n = 0; n < 2; ++n)
        acc[m][n] = mfma16(af[m], bfr[n], acc[m][n]);
    __syncthreads();
  }
  const int gq = lane >> 4;
#pragma unroll
  for (int m = 0; m < 4; ++m) {
#pragma unroll
    for (int n = 0; n < 2; ++n) {
      int gcol = bn + wn + n * 16 + lr;
      f32x4 v = acc[m][n];
#pragma unroll
      for (int rr = 0; rr < 4; ++rr) {
        int grow = bm + wm + m * 16 + gq * 4 + rr;
        float x = v[rr];
        if constexpr (EPI == 2) {
          x += b0[gcol] + res[(size_t)grow * N + gcol];
        } else {
          x += b0[gcol] + pos[(size_t)(grow & (SEQ - 1)) * N + gcol] + tok[gcol];
        }
        Cf[(size_t)grow * N + gcol] = x;
      }
    }
  }
}

// --------------- LayerNorm: wave-per-row, float4 loads, shuffle-only reduce ---------------
typedef short bf16x4v __attribute__((ext_vector_type(4)));
__global__ __launch_bounds__(256) void k_ln(const float* __restrict__ in,
                                            const float* __restrict__ g, const float* __restrict__ b,
                                            float* __restrict__ xf, bf16* __restrict__ xb) {
  const int wv = threadIdx.x >> 6, lane = threadIdx.x & 63;
  const int row = blockIdx.x * 4 + wv;
  const float4* rp = (const float4*)(in + (size_t)row * DM);
  float4 v[3];
  float s = 0.f, s2 = 0.f;
#pragma unroll
  for (int i = 0; i < 3; ++i) {
    float4 t = rp[i * 64 + lane];
    v[i] = t;
    s += t.x + t.y + t.z + t.w;
    s2 += t.x * t.x + t.y * t.y + t.z * t.z + t.w * t.w;
  }
#pragma unroll
  for (int off = 1; off < 64; off <<= 1) {
    s += __shfl_xor(s, off);
    s2 += __shfl_xor(s2, off);
  }
  const float mean = s * (1.0f / DM);
  const float var = s2 * (1.0f / DM) - mean * mean;
  const float rs = rsqrtf(var + 1e-12f);
  float4* xfp = (float4*)(xf + (size_t)row * DM);
  bf16* xbp = xb + (size_t)row * DM;
#pragma unroll
  for (int i = 0; i < 3; ++i) {
    const int c4 = i * 64 + lane;
    float4 g4 = ((const float4*)g)[c4];
    float4 b4 = ((const float4*)b)[c4];
    float4 y;
    y.x = (v[i].x - mean) * rs * g4.x + b4.x;
    y.y = (v[i].y - mean) * rs * g4.y + b4.y;
    y.z = (v[i].z - mean) * rs * g4.z + b4.z;
    y.w = (v[i].w - mean) * rs * g4.w + b4.w;
    xfp[c4] = y;
    bf16 t4[4];
    t4[0] = __float2bfloat16(y.x); t4[1] = __float2bfloat16(y.y);
    t4[2] = __float2bfloat16(y.z); t4[3] = __float2bfloat16(y.w);
    *(bf16x4v*)(xbp + c4 * 4) = *(bf16x4v*)t4;
  }
}

// ------------------- V transpose: qkv v-section (B,S,H,DH) -> vt (B,H,DH,S) -------------------
__global__ __launch_bounds__(256) void k_vt(const bf16* __restrict__ qkv, bf16* __restrict__ vt) {
  __shared__ unsigned short t[64][72];
  const int bh = blockIdx.y, t0 = blockIdx.x * 64;
  const int b = bh / NH, h = bh - b * NH;
  const int tid = threadIdx.x;
  const int rr = tid >> 2, cs = (tid & 3) * 16;
  const unsigned short* src = (const unsigned short*)qkv +
      (size_t)(b * SEQ + t0 + rr) * QKVN + 2 * DM + h * DHD + cs;
#pragma unroll
  for (int i = 0; i < 16; ++i) t[cs + i][rr] = src[i];
  __syncthreads();
  unsigned short* dst = (unsigned short*)vt + (size_t)(bh * DHD + rr) * SEQ + t0 + cs;
#pragma unroll
  for (int i = 0; i < 16; ++i) dst[i] = t[rr][cs + i];
}

// ----------------------------- block-sparse attention -----------------------------
__global__ __launch_bounds__(256) void k_attn(
    const bf16* __restrict__ qkv, const bf16* __restrict__ vt,
    const int* __restrict__ blk_idx,
    bf16* __restrict__ ctx, float* __restrict__ epart) {
  __shared__ __align__(16) bf16 sQ[64 * 64];
  __shared__ __align__(16) bf16 sK[2][64 * 64];
  __shared__ __align__(16) bf16 sV[2][64 * 64];
  __shared__ __align__(16) bf16 sP[4][16 * 64];
  const int job = blockIdx.x;
  const int b = job / (NH * NJOBS);
  const int rem = job - b * NH * NJOBS;
  const int h = rem / NJOBS;
  const int j = rem - h * NJOBS;
  const int tid = threadIdx.x, lane = tid & 63, w = tid >> 6;
  const int lr = lane & 15, lks = lane >> 4;

  const bool interior = (j < 62);
  int qblk, e = 0, split = 0;
  if (interior) qblk = j + 1;
  else { int tt = j - 62; e = tt >> 3; split = tt & 7; qblk = e ? NBLK - 1 : 0; }
  const int qt0 = qblk * 64;

  const int skip_pos = interior ? (j == 0 ? 2 : (j == 61 ? 4 : 8)) : 8;
  const int nkb = (skip_pos < 8) ? 7 : 8;
  auto kbi_of = [&](int i) {
    int kb = i + (i >= skip_pos ? 1 : 0);
    return interior ? blk_idx[j * 8 + kb] : split * 8 + kb;
  };

  const bf16* kbase0 = qkv + (size_t)b * SEQ * QKVN + DM + h * DHD;
  const bf16* vbase0 = vt + (size_t)((b * NH + h) * DHD) * SEQ;
  auto stageKV = [&](int buf, int kbi) {
    const int kt0 = kbi * 64;
#pragma unroll
    for (int ss = 0; ss < 2; ++ss) {
      int seg = tid + ss * 256;
      int row = seg >> 3, slot = seg & 7;
      int kseg = slot ^ (row & 7);
      gload_lds16(kbase0 + (size_t)(kt0 + row) * QKVN + kseg * 8, &sK[buf][seg * 8]);
      gload_lds16(vbase0 + (size_t)row * SEQ + kt0 + kseg * 8, &sV[buf][seg * 8]);
    }
  };

  {
    const bf16* qbase = qkv + (size_t)(b * SEQ + qt0) * QKVN + h * DHD;
#pragma unroll
    for (int ss = 0; ss < 2; ++ss) {
      int seg = tid + ss * 256;
      int row = seg >> 3, slot = seg & 7;
      int kseg = slot ^ (row & 7);
      gload_lds16(qbase + (size_t)row * QKVN + kseg * 8, sQ + seg * 8);
    }
  }
  stageKV(0, kbi_of(0));
  __syncthreads();
  bf16x8 aq[2];
#pragma unroll
  for (int kk = 0; kk < 2; ++kk) {
    int rq = w * 16 + lr;
    int slot = (kk * 4 + lks) ^ (rq & 7);
    aq[kk] = *(const bf16x8*)(sQ + rq * 64 + slot * 8);
  }

  float m_r[4], l_r[4];
  f32x4 o[4] = {};
#pragma unroll
  for (int r = 0; r < 4; ++r) { m_r[r] = -1e30f; l_r[r] = 0.f; }

  for (int i = 0; i < nkb; ++i) {
    const int buf = i & 1;
    if (i + 1 < nkb) stageKV(buf ^ 1, kbi_of(i + 1));
    f32x4 sfr[4];
#pragma unroll
    for (int n = 0; n < 4; ++n) {
      f32x4 z = {};
#pragma unroll
      for (int kk = 0; kk < 2; ++kk) {
        int rk = n * 16 + lr;
        int slot = (kk * 4 + lks) ^ (rk & 7);
        bf16x8 kf = *(const bf16x8*)(&sK[buf][rk * 64 + slot * 8]);
        z = mfma16(aq[kk], kf, z);
      }
      sfr[n] = z;
    }
#pragma unroll
    for (int n = 0; n < 4; ++n)
#pragma unroll
      for (int r = 0; r < 4; ++r) sfr[n][r] *= 0.125f;
    float alpha[4];
#pragma unroll
    for (int r = 0; r < 4; ++r) {
      float tmx = fmaxf(fmaxf(sfr[0][r], sfr[1][r]), fmaxf(sfr[2][r], sfr[3][r]));
#pragma unroll
      for (int off = 1; off < 16; off <<= 1) tmx = fmaxf(tmx, __shfl_xor(tmx, off));
      float mnew = fmaxf(m_r[r], tmx);
      alpha[r] = __expf(m_r[r] - mnew);
      m_r[r] = mnew;
    }
#pragma unroll
    for (int r = 0; r < 4; ++r) {
      float su = 0.f;
#pragma unroll
      for (int n = 0; n < 4; ++n) {
        float p = __expf(sfr[n][r] - m_r[r]);
        sfr[n][r] = p;
        su += p;
      }
#pragma unroll
      for (int off = 1; off < 16; off <<= 1) su += __shfl_xor(su, off);
      l_r[r] = l_r[r] * alpha[r] + su;
    }
#pragma unroll
    for (int n = 0; n < 4; ++n) {
#pragma unroll
      for (int r = 0; r < 4; ++r) {
        int prow = lks * 4 + r;
        int col = n * 16 + lr;
        int eo = prow * 64 + ((((col >> 3) ^ (prow & 7)) << 3) | (col & 7));
        sP[w][eo] = __float2bfloat16(sfr[n][r]);
      }
    }
#pragma unroll
    for (int n = 0; n < 4; ++n)
#pragma unroll
      for (int r = 0; r < 4; ++r) o[n][r] *= alpha[r];
    asm volatile("s_waitcnt lgkmcnt(0)" ::: "memory");
    __builtin_amdgcn_sched_barrier(0);
    bf16x8 pa[2];
#pragma unroll
    for (int kk = 0; kk < 2; ++kk) {
      int slot = (kk * 4 + lks) ^ (lr & 7);
      pa[kk] = *(const bf16x8*)(sP[w] + lr * 64 + slot * 8);
    }
#pragma unroll
    for (int n = 0; n < 4; ++n) {
#pragma unroll
      for (int kk = 0; kk < 2; ++kk) {
        int rv = n * 16 + lr;
        int slot = (kk * 4 + lks) ^ (rv & 7);
        bf16x8 vf = *(const bf16x8*)(&sV[buf][rv * 64 + slot * 8]);
        o[n] = mfma16(pa[kk], vf, o[n]);
      }
    }
    __syncthreads();
  }
  if (interior) {
#pragma unroll
    for (int r = 0; r < 4; ++r) {
      float inv = 1.0f / l_r[r];
      int tok = qt0 + w * 16 + lks * 4 + r;
#pragma unroll
      for (int n = 0; n < 4; ++n) {
        int col = h * DHD + n * 16 + lr;
        ctx[(size_t)(b * SEQ + tok) * DM + col] = __float2bfloat16(o[n][r] * inv);
      }
    }
  } else {
    float* base = epart + (size_t)((((b * NH + h) * 2 + e) * 8) + split) * PARTF;
#pragma unroll
    for (int r = 0; r < 4; ++r) {
      int qrow = w * 16 + lks * 4 + r;
#pragma unroll
      for (int n = 0; n < 4; ++n)
        base[qrow * 64 + n * 16 + lr] = o[n][r];
      if (lr == 0) { base[4096 + qrow] = m_r[r]; base[4096 + 64 + qrow] = l_r[r]; }
    }
  }
}

// ----------------------------- edge split-K combine -----------------------------
__global__ __launch_bounds__(256) void k_combine(const float* __restrict__ epart,
                                                 bf16* __restrict__ ctx) {
  const int bid = blockIdx.x;
  const int b = bid / (NH * 2);
  const int rem = bid - b * NH * 2;
  const int h = rem >> 1, e = rem & 1;
  const int tid = threadIdx.x;
  const int row = tid >> 2, cq = tid & 3;
  const float* base0 = epart + (size_t)(((b * NH + h) * 2 + e) * 8) * PARTF;
  float ms[8], ls[8], M = -1e30f;
#pragma unroll
  for (int s = 0; s < 8; ++s) {
    const float* bp = base0 + (size_t)s * PARTF;
    ms[s] = bp[4096 + row];
    ls[s] = bp[4096 + 64 + row];
    M = fmaxf(M, ms[s]);
  }
  float Lt = 0.f, accv[16];
#pragma unroll
  for (int i = 0; i < 16; ++i) accv[i] = 0.f;
#pragma unroll
  for (int s = 0; s < 8; ++s) {
    float wgt = __expf(ms[s] - M);
    Lt += ls[s] * wgt;
    const float* op = base0 + (size_t)s * PARTF + row * 64 + cq * 16;
#pragma unroll
    for (int i = 0; i < 16; ++i) accv[i] += op[i] * wgt;
  }
  float inv = 1.0f / Lt;
  int qblk = e ? NBLK - 1 : 0;
  int tok = qblk * 64 + row;
  bf16* cp = ctx + (size_t)(b * SEQ + tok) * DM + h * DHD + cq * 16;
#pragma unroll
  for (int i = 0; i < 16; ++i) cp[i] = __float2bfloat16(accv[i] * inv);
}

// ----------------------------- classifier: x[:,0,:] @ Wc + bc -----------------------------
__global__ void k_classifier(const float* __restrict__ xf, const float* __restrict__ Wc,
                             const float* __restrict__ bc, float* __restrict__ out) {
  const int tid = threadIdx.x, lane = tid & 63, wv = tid >> 6;
  const int b = wv >> 1, c = wv & 1;
  float s = 0.f;
  for (int d = lane; d < DM; d += 64)
    s += xf[(size_t)(b * SEQ) * DM + d] * Wc[d * NCLS + c];
#pragma unroll
  for (int off = 32; off > 0; off >>= 1) s += __shfl_down(s, off);
  if (lane == 0) out[b * NCLS + c] = s + bc[c];
}

// ----------------------------- host launch -----------------------------
extern "C" void kernel_launch(void* const* d_in, const int* in_sizes, int n_in,
                              void* d_out, int out_size, void* d_ws, size_t ws_size,
                              hipStream_t stream) {
  const float* embeddings = (const float*)d_in[0];
  const float* Wp  = (const float*)d_in[2];
  const float* bp  = (const float*)d_in[3];
  const float* pos = (const float*)d_in[4];
  const float* tokv = (const float*)d_in[5];
  const float* lng = (const float*)d_in[6];
  const float* lnb = (const float*)d_in[7];
  const float* Wq  = (const float*)d_in[8];
  const float* bq  = (const float*)d_in[9];
  const float* Wk  = (const float*)d_in[10];
  const float* bk  = (const float*)d_in[11];
  const float* Wv  = (const float*)d_in[12];
  const float* bv  = (const float*)d_in[13];
  const float* Wo  = (const float*)d_in[14];
  const float* bo  = (const float*)d_in[15];
  const float* l1g = (const float*)d_in[16];
  const float* l1b = (const float*)d_in[17];
  const float* W1  = (const float*)d_in[18];
  const float* b1  = (const float*)d_in[19];
  const float* W2  = (const float*)d_in[20];
  const float* b2  = (const float*)d_in[21];
  const float* l2g = (const float*)d_in[22];
  const float* l2b = (const float*)d_in[23];
  const float* Wc  = (const float*)d_in[24];
  const float* bc  = (const float*)d_in[25];
  const int*  bidx = (const int*)d_in[26];
  (void)in_sizes; (void)n_in; (void)out_size; (void)ws_size;

  char* ws = (char*)d_ws;
  size_t off = 0;
  auto alloc = [&](size_t bytes) -> char* {
    char* p = ws + off;
    off += (bytes + 255) & ~(size_t)255;
    return p;
  };
  bf16*  embB  = (bf16*)alloc((size_t)MR * INPD * 2);
  bf16*  wpT   = (bf16*)alloc((size_t)DM * INPD * 2);
  bf16*  wqkvT = (bf16*)alloc((size_t)QKVN * DM * 2);
  bf16*  woT   = (bf16*)alloc((size_t)DM * DM * 2);
  bf16*  w1T   = (bf16*)alloc((size_t)FFD * DM * 2);
  bf16*  w2T   = (bf16*)alloc((size_t)DM * FFD * 2);
  float* xf    = (float*)alloc((size_t)MR * DM * 4);
  bf16*  xb    = (bf16*)alloc((size_t)MR * DM * 2);
  float* preLN = (float*)alloc((size_t)MR * DM * 4);
  bf16*  qkvB  = (bf16*)alloc((size_t)MR * QKVN * 2);
  bf16*  vtB   = (bf16*)alloc((size_t)BATCH * NH * DHD * SEQ * 2);
  bf16*  ctxB  = (bf16*)alloc((size_t)MR * DM * 2);
  bf16*  hB    = (bf16*)alloc((size_t)MR * FFD * 2);
  float* epart = (float*)alloc((size_t)BATCH * NH * 2 * 8 * PARTF * 4);

  // embed: x = emb @ Wp + bp + pos + tok, then LN
  k_f32_to_bf16<<<2048, 256, 0, stream>>>(embeddings, embB, MR * INPD);
  k_transpose_one<<<(INPD / 32) * (DM / 32), 256, 0, stream>>>(Wp, wpT, INPD, DM);
  k_gemm_n64<3><<<dim3(DM / 64, MR / 128), 256, 0, stream>>>(embB, wpT, DM, INPD,
      bp, nullptr, pos, tokv, preLN);
  k_ln<<<MR / 4, 256, 0, stream>>>(preLN, lng, lnb, xf, xb);

  for (int l = 0; l < NL; ++l) {
    k_transpose_layer<<<6912, 256, 0, stream>>>(Wq, Wk, Wv, Wo, W1, W2,
        wqkvT, woT, w1T, w2T, l);
    k_gemm<0><<<dim3(QKVN / 128, MR / 128), 256, 0, stream>>>(xb, wqkvT, QKVN, DM,
        bq + (size_t)l * DM, bk + (size_t)l * DM, bv + (size_t)l * DM, qkvB);
    k_vt<<<dim3(SEQ / 64, BATCH * NH), 256, 0, stream>>>(qkvB, vtB);
    k_attn<<<BATCH * NH * NJOBS, 256, 0, stream>>>(qkvB, vtB, bidx, ctxB, epart);
    k_combine<<<BATCH * NH * 2, 256, 0, stream>>>(epart, ctxB);
    k_gemm_n64<2><<<dim3(DM / 64, MR / 128), 256, 0, stream>>>(ctxB, woT, DM, DM,
        bo + (size_t)l * DM, xf, nullptr, nullptr, preLN);
    k_ln<<<MR / 4, 256, 0, stream>>>(preLN, l1g + (size_t)l * DM, l1b + (size_t)l * DM, xf, xb);
    k_gemm<1><<<dim3(FFD / 128, MR / 128), 256, 0, stream>>>(xb, w1T, FFD, DM,
        b1 + (size_t)l * FFD, nullptr, nullptr, hB);
    k_gemm_n64<2><<<dim3(DM / 64, MR / 128), 256, 0, stream>>>(hB, w2T, DM, FFD,
        b2 + (size_t)l * DM, xf, nullptr, nullptr, preLN);
    k_ln<<<MR / 4, 256, 0, stream>>>(preLN, l2g + (size_t)l * DM, l2b + (size_t)l * DM, xf, xb);
  }
  k_classifier<<<1, 256, 0, stream>>>(xf, Wc, bc, (float*)d_out);
}

// Round 7
// 3494.632 us; speedup vs baseline: 1.2561x; 1.0658x over previous
//
#include <hip/hip_runtime.h>
#include <hip/hip_bf16.h>
#include <math.h>

using bf16 = __hip_bfloat16;
typedef short bf16x8 __attribute__((ext_vector_type(8)));
typedef float f32x4 __attribute__((ext_vector_type(4)));
typedef unsigned short u16x4 __attribute__((ext_vector_type(4)));

#define DEV __device__ __forceinline__

constexpr int BATCH = 2, SEQ = 4096, INPD = 1280, DM = 768, FFD = 3072;
constexpr int NL = 12, NH = 12, DHD = 64, NBLK = 64, NCLS = 2;
constexpr int MR = BATCH * SEQ;       // 8192 token rows
constexpr int QKVN = 3 * DM;          // 2304
constexpr int NJOBS = 62 + 16;        // interior blocks + 2 edges * 8 splits
constexpr int PARTF = 64 * 64 + 128;  // floats per edge partial (O + m + l)

DEV void gload_lds16(const void* g, void* l) {
  __builtin_amdgcn_global_load_lds(
      (const __attribute__((address_space(1))) unsigned int*)g,
      (__attribute__((address_space(3))) unsigned int*)l, 16, 0, 0);
}

DEV f32x4 mfma16(bf16x8 a, bf16x8 b, f32x4 c) {
  return __builtin_amdgcn_mfma_f32_16x16x32_bf16(a, b, c, 0, 0, 0);
}

DEV float b2f(unsigned short u) { return __uint_as_float((unsigned)u << 16); }
DEV unsigned short f2b(float x) {
  bf16 h = __float2bfloat16(x);
  return *(unsigned short*)&h;
}

// XCD-chunked bijective block swizzle (m204).
DEV int xcd_swizzle(int orig, int nwg) {
  int q = nwg >> 3, r = nwg & 7;
  int xcd = orig & 7, pos_ = orig >> 3;
  return (xcd < r ? xcd * (q + 1) : r * (q + 1) + (xcd - r) * q) + pos_;
}

// ----------------------------- f32 -> bf16 convert (16B stores) -----------------------------
__global__ void k_f32_to_bf16(const float* __restrict__ in, bf16* __restrict__ out, int n) {
  int i = (blockIdx.x * blockDim.x + threadIdx.x) * 8;
  int stride = gridDim.x * blockDim.x * 8;
  for (; i < n; i += stride) {
    float4 a = *(const float4*)(in + i);
    float4 b = *(const float4*)(in + i + 4);
    bf16 t8[8];
    t8[0] = __float2bfloat16(a.x); t8[1] = __float2bfloat16(a.y);
    t8[2] = __float2bfloat16(a.z); t8[3] = __float2bfloat16(a.w);
    t8[4] = __float2bfloat16(b.x); t8[5] = __float2bfloat16(b.y);
    t8[6] = __float2bfloat16(b.z); t8[7] = __float2bfloat16(b.w);
    *(bf16x8*)(out + i) = *(bf16x8*)t8;
  }
}

// ------------------------- weight transpose (K,N)f32 -> (N,K)bf16 -------------------------
DEV void tr32_tile(const float* __restrict__ src, bf16* __restrict__ dst,
                   int K, int N, int tile, float t[32][33], int tid) {
  int nt = N >> 5;
  int tk = tile / nt, tn = tile - tk * nt;
  int tx = tid & 31, ty = tid >> 5;
#pragma unroll
  for (int i = 0; i < 4; ++i)
    t[ty + 8 * i][tx] = src[(size_t)(tk * 32 + ty + 8 * i) * N + tn * 32 + tx];
  __syncthreads();
#pragma unroll
  for (int i = 0; i < 4; ++i)
    dst[(size_t)(tn * 32 + ty + 8 * i) * K + tk * 32 + tx] = __float2bfloat16(t[tx][ty + 8 * i]);
}

__global__ __launch_bounds__(256) void k_transpose_one(const float* __restrict__ src,
                                                       bf16* __restrict__ dst, int K, int N) {
  __shared__ float t[32][33];
  tr32_tile(src, dst, K, N, blockIdx.x, t, threadIdx.x);
}

__global__ __launch_bounds__(256) void k_transpose_layer(
    const float* __restrict__ Wq, const float* __restrict__ Wk,
    const float* __restrict__ Wv, const float* __restrict__ Wo,
    const float* __restrict__ W1, const float* __restrict__ W2,
    bf16* __restrict__ wqkvT, bf16* __restrict__ woT,
    bf16* __restrict__ w1T, bf16* __restrict__ w2T, int l) {
  __shared__ float t[32][33];
  int id = blockIdx.x;
  const float* src; bf16* dst; int K, N;
  if (id < 1728) {               // Wq,Wk,Wv -> concatenated (2304 x 768)
    int m = id / 576; id -= m * 576;
    src = (m == 0 ? Wq : m == 1 ? Wk : Wv) + (size_t)l * DM * DM;
    dst = wqkvT + (size_t)m * DM * DM; K = DM; N = DM;
  } else if (id < 2304) {
    id -= 1728; src = Wo + (size_t)l * DM * DM; dst = woT; K = DM; N = DM;
  } else if (id < 4608) {
    id -= 2304; src = W1 + (size_t)l * DM * FFD; dst = w1T; K = DM; N = FFD;
  } else {
    id -= 4608; src = W2 + (size_t)l * FFD * DM; dst = w2T; K = FFD; N = DM;
  }
  tr32_tile(src, dst, K, N, id, t, threadIdx.x);
}

// -------------------- 128^2 GEMM (2-phase, proven round-3): C = A * BT^T --------------------
// All epilogues now write bf16 raw output (residual add fused into k_ln_res).
// EPI: 0 = +segmented-bias(q/k/v) ; 1 = +bias, gelu ; 2 = +bias ; 3 = +bias +pos +tok (embed)
template <int EPI>
__global__ __launch_bounds__(256) void k_gemm(
    const bf16* __restrict__ A, const bf16* __restrict__ BT, int N, int K,
    const float* __restrict__ b0, const float* __restrict__ b1, const float* __restrict__ b2,
    const float* __restrict__ pos, const float* __restrict__ tok,
    bf16* __restrict__ Cb) {
  __shared__ __align__(16) bf16 lA[2][128 * 32];
  __shared__ __align__(16) bf16 lB[2][128 * 32];
  const int tid = threadIdx.x;
  const int gx = gridDim.x;
  const int tile = xcd_swizzle(blockIdx.y * gx + blockIdx.x, gx * gridDim.y);
  const int bx = tile % gx, by = tile / gx;
  const int bm = by * 128, bn = bx * 128;
  const int lane = tid & 63, wid = tid >> 6;
  const int wm = (wid >> 1) * 64, wn = (wid & 1) * 64;
  const int lr = lane & 15, lks = lane >> 4;
  const bf16* Abase = A + (size_t)bm * K;
  const bf16* Bbase = BT + (size_t)bn * K;

  // stage 128x32 tiles; dest linear (gload_lds), source slot pre-swizzled
  // (slot ^= (row>>1)&3) so swizzled ds_read_b128 is 2-way max (free, m136).
  auto stage = [&](int buf, int t) {
    int k0 = t << 5;
#pragma unroll
    for (int ss = 0; ss < 2; ++ss) {
      int seg = tid + ss * 256;
      int row = seg >> 2, slot = seg & 3;
      int kseg = slot ^ ((row >> 1) & 3);
      gload_lds16(Abase + (size_t)row * K + k0 + kseg * 8, &lA[buf][seg * 8]);
      gload_lds16(Bbase + (size_t)row * K + k0 + kseg * 8, &lB[buf][seg * 8]);
    }
  };

  f32x4 acc[4][4] = {};
  const int nt = K >> 5;
  stage(0, 0);
  __syncthreads();
  for (int t = 0; t < nt; ++t) {
    const int buf = t & 1;
    if (t + 1 < nt) stage(buf ^ 1, t + 1);  // prefetch next tile under compute
    bf16x8 af[4], bfr[4];
#pragma unroll
    for (int m = 0; m < 4; ++m) {
      int rr = wm + m * 16 + lr;
      af[m] = *(const bf16x8*)(&lA[buf][rr * 32 + ((lks ^ ((rr >> 1) & 3)) << 3)]);
    }
#pragma unroll
    for (int n = 0; n < 4; ++n) {
      int rr = wn + n * 16 + lr;
      bfr[n] = *(const bf16x8*)(&lB[buf][rr * 32 + ((lks ^ ((rr >> 1) & 3)) << 3)]);
    }
#pragma unroll
    for (int m = 0; m < 4; ++m)
#pragma unroll
      for (int n = 0; n < 4; ++n)
        acc[m][n] = mfma16(af[m], bfr[n], acc[m][n]);
    __syncthreads();
  }
  const int gq = lane >> 4;
#pragma unroll
  for (int m = 0; m < 4; ++m) {
#pragma unroll
    for (int n = 0; n < 4; ++n) {
      int gcol = bn + wn + n * 16 + lr;
      f32x4 v = acc[m][n];
#pragma unroll
      for (int rr = 0; rr < 4; ++rr) {
        int grow = bm + wm + m * 16 + gq * 4 + rr;
        float x = v[rr];
        if constexpr (EPI == 0) {
          int c = gcol; const float* bb = b0;
          if (c >= 2 * DM) { bb = b2; c -= 2 * DM; }
          else if (c >= DM) { bb = b1; c -= DM; }
          x += bb[c];
        } else if constexpr (EPI == 1) {
          x += b0[gcol];
          x = 0.5f * x * (1.0f + erff(x * 0.70710678118654752f));
        } else if constexpr (EPI == 2) {
          x += b0[gcol];
        } else {
          x += b0[gcol] + pos[(size_t)(grow & (SEQ - 1)) * N + gcol] + tok[gcol];
        }
        Cb[(size_t)grow * N + gcol] = __float2bfloat16(x);
      }
    }
  }
}

// ------- fused residual-add + LayerNorm, all-bf16 streams, wave-per-row, in-place safe -------
// out = LN(gout + res) (res optional). res/out may alias (each row read+written by one wave).
template <bool HASRES>
__global__ __launch_bounds__(256) void k_ln_res(
    const bf16* __restrict__ gout, const bf16* res,
    const float* __restrict__ g, const float* __restrict__ b,
    bf16* out) {
  const int wv = threadIdx.x >> 6, lane = threadIdx.x & 63;
  const int row = blockIdx.x * 4 + wv;
  const unsigned short* gp = (const unsigned short*)gout + (size_t)row * DM;
  const unsigned short* rp = (const unsigned short*)res + (size_t)row * DM;
  float v[12];
  float s = 0.f, s2 = 0.f;
#pragma unroll
  for (int i = 0; i < 3; ++i) {
    const int c = i * 256 + lane * 4;
    u16x4 a4 = *(const u16x4*)(gp + c);
    u16x4 r4;
    if constexpr (HASRES) r4 = *(const u16x4*)(rp + c);
#pragma unroll
    for (int k2 = 0; k2 < 4; ++k2) {
      float x = b2f(a4[k2]);
      if constexpr (HASRES) x += b2f(r4[k2]);
      v[i * 4 + k2] = x;
      s += x; s2 += x * x;
    }
  }
#pragma unroll
  for (int off = 1; off < 64; off <<= 1) {
    s += __shfl_xor(s, off);
    s2 += __shfl_xor(s2, off);
  }
  const float mean = s * (1.0f / DM);
  const float var = s2 * (1.0f / DM) - mean * mean;
  const float rs = rsqrtf(var + 1e-12f);
  unsigned short* op = (unsigned short*)out + (size_t)row * DM;
#pragma unroll
  for (int i = 0; i < 3; ++i) {
    const int c = i * 256 + lane * 4;
    float4 g4 = *(const float4*)(g + c);
    float4 b4 = *(const float4*)(b + c);
    u16x4 o4;
    o4[0] = f2b((v[i * 4 + 0] - mean) * rs * g4.x + b4.x);
    o4[1] = f2b((v[i * 4 + 1] - mean) * rs * g4.y + b4.y);
    o4[2] = f2b((v[i * 4 + 2] - mean) * rs * g4.z + b4.z);
    o4[3] = f2b((v[i * 4 + 3] - mean) * rs * g4.w + b4.w);
    *(u16x4*)(op + c) = o4;
  }
}

// ------------------- V transpose: qkv v-section (B,S,H,DH) -> vt (B,H,DH,S) -------------------
__global__ __launch_bounds__(256) void k_vt(const bf16* __restrict__ qkv, bf16* __restrict__ vt) {
  __shared__ unsigned short t[64][72];
  const int bh = blockIdx.y, t0 = blockIdx.x * 64;
  const int b = bh / NH, h = bh - b * NH;
  const int tid = threadIdx.x;
  const int rr = tid >> 2, cs = (tid & 3) * 16;
  const unsigned short* src = (const unsigned short*)qkv +
      (size_t)(b * SEQ + t0 + rr) * QKVN + 2 * DM + h * DHD + cs;
#pragma unroll
  for (int i = 0; i < 16; ++i) t[cs + i][rr] = src[i];
  __syncthreads();
  unsigned short* dst = (unsigned short*)vt + (size_t)(bh * DHD + rr) * SEQ + t0 + cs;
#pragma unroll
  for (int i = 0; i < 16; ++i) dst[i] = t[rr][cs + i];
}

// ----------------------------- block-sparse attention -----------------------------
__global__ __launch_bounds__(256) void k_attn(
    const bf16* __restrict__ qkv, const bf16* __restrict__ vt,
    const int* __restrict__ blk_idx,
    bf16* __restrict__ ctx, float* __restrict__ epart) {
  __shared__ __align__(16) bf16 sQ[64 * 64];
  __shared__ __align__(16) bf16 sK[2][64 * 64];
  __shared__ __align__(16) bf16 sV[2][64 * 64];
  __shared__ __align__(16) bf16 sP[4][16 * 64];
  const int job = blockIdx.x;
  const int b = job / (NH * NJOBS);
  const int rem = job - b * NH * NJOBS;
  const int h = rem / NJOBS;
  const int j = rem - h * NJOBS;
  const int tid = threadIdx.x, lane = tid & 63, w = tid >> 6;
  const int lr = lane & 15, lks = lane >> 4;

  const bool interior = (j < 62);
  int qblk, e = 0, split = 0;
  if (interior) qblk = j + 1;
  else { int tt = j - 62; e = tt >> 3; split = tt & 7; qblk = e ? NBLK - 1 : 0; }
  const int qt0 = qblk * 64;

  const int skip_pos = interior ? (j == 0 ? 2 : (j == 61 ? 4 : 8)) : 8;
  const int nkb = (skip_pos < 8) ? 7 : 8;
  auto kbi_of = [&](int i) {
    int kb = i + (i >= skip_pos ? 1 : 0);
    return interior ? blk_idx[j * 8 + kb] : split * 8 + kb;
  };

  const bf16* kbase0 = qkv + (size_t)b * SEQ * QKVN + DM + h * DHD;
  const bf16* vbase0 = vt + (size_t)((b * NH + h) * DHD) * SEQ;
  auto stageKV = [&](int buf, int kbi) {
    const int kt0 = kbi * 64;
#pragma unroll
    for (int ss = 0; ss < 2; ++ss) {
      int seg = tid + ss * 256;
      int row = seg >> 3, slot = seg & 7;
      int kseg = slot ^ (row & 7);
      gload_lds16(kbase0 + (size_t)(kt0 + row) * QKVN + kseg * 8, &sK[buf][seg * 8]);
      gload_lds16(vbase0 + (size_t)row * SEQ + kt0 + kseg * 8, &sV[buf][seg * 8]);
    }
  };

  {
    const bf16* qbase = qkv + (size_t)(b * SEQ + qt0) * QKVN + h * DHD;
#pragma unroll
    for (int ss = 0; ss < 2; ++ss) {
      int seg = tid + ss * 256;
      int row = seg >> 3, slot = seg & 7;
      int kseg = slot ^ (row & 7);
      gload_lds16(qbase + (size_t)row * QKVN + kseg * 8, sQ + seg * 8);
    }
  }
  stageKV(0, kbi_of(0));
  __syncthreads();
  bf16x8 aq[2];
#pragma unroll
  for (int kk = 0; kk < 2; ++kk) {
    int rq = w * 16 + lr;
    int slot = (kk * 4 + lks) ^ (rq & 7);
    aq[kk] = *(const bf16x8*)(sQ + rq * 64 + slot * 8);
  }

  float m_r[4], l_r[4];
  f32x4 o[4] = {};
#pragma unroll
  for (int r = 0; r < 4; ++r) { m_r[r] = -1e30f; l_r[r] = 0.f; }

  for (int i = 0; i < nkb; ++i) {
    const int buf = i & 1;
    if (i + 1 < nkb) stageKV(buf ^ 1, kbi_of(i + 1));
    f32x4 sfr[4];
#pragma unroll
    for (int n = 0; n < 4; ++n) {
      f32x4 z = {};
#pragma unroll
      for (int kk = 0; kk < 2; ++kk) {
        int rk = n * 16 + lr;
        int slot = (kk * 4 + lks) ^ (rk & 7);
        bf16x8 kf = *(const bf16x8*)(&sK[buf][rk * 64 + slot * 8]);
        z = mfma16(aq[kk], kf, z);
      }
      sfr[n] = z;
    }
#pragma unroll
    for (int n = 0; n < 4; ++n)
#pragma unroll
      for (int r = 0; r < 4; ++r) sfr[n][r] *= 0.125f;
    float alpha[4];
#pragma unroll
    for (int r = 0; r < 4; ++r) {
      float tmx = fmaxf(fmaxf(sfr[0][r], sfr[1][r]), fmaxf(sfr[2][r], sfr[3][r]));
#pragma unroll
      for (int off = 1; off < 16; off <<= 1) tmx = fmaxf(tmx, __shfl_xor(tmx, off));
      float mnew = fmaxf(m_r[r], tmx);
      alpha[r] = __expf(m_r[r] - mnew);
      m_r[r] = mnew;
    }
#pragma unroll
    for (int r = 0; r < 4; ++r) {
      float su = 0.f;
#pragma unroll
      for (int n = 0; n < 4; ++n) {
        float p = __expf(sfr[n][r] - m_r[r]);
        sfr[n][r] = p;
        su += p;
      }
#pragma unroll
      for (int off = 1; off < 16; off <<= 1) su += __shfl_xor(su, off);
      l_r[r] = l_r[r] * alpha[r] + su;
    }
#pragma unroll
    for (int n = 0; n < 4; ++n) {
#pragma unroll
      for (int r = 0; r < 4; ++r) {
        int prow = lks * 4 + r;
        int col = n * 16 + lr;
        int eo = prow * 64 + ((((col >> 3) ^ (prow & 7)) << 3) | (col & 7));
        sP[w][eo] = __float2bfloat16(sfr[n][r]);
      }
    }
#pragma unroll
    for (int n = 0; n < 4; ++n)
#pragma unroll
      for (int r = 0; r < 4; ++r) o[n][r] *= alpha[r];
    asm volatile("s_waitcnt lgkmcnt(0)" ::: "memory");
    __builtin_amdgcn_sched_barrier(0);
    bf16x8 pa[2];
#pragma unroll
    for (int kk = 0; kk < 2; ++kk) {
      int slot = (kk * 4 + lks) ^ (lr & 7);
      pa[kk] = *(const bf16x8*)(sP[w] + lr * 64 + slot * 8);
    }
#pragma unroll
    for (int n = 0; n < 4; ++n) {
#pragma unroll
      for (int kk = 0; kk < 2; ++kk) {
        int rv = n * 16 + lr;
        int slot = (kk * 4 + lks) ^ (rv & 7);
        bf16x8 vf = *(const bf16x8*)(&sV[buf][rv * 64 + slot * 8]);
        o[n] = mfma16(pa[kk], vf, o[n]);
      }
    }
    __syncthreads();
  }
  if (interior) {
#pragma unroll
    for (int r = 0; r < 4; ++r) {
      float inv = 1.0f / l_r[r];
      int tok = qt0 + w * 16 + lks * 4 + r;
#pragma unroll
      for (int n = 0; n < 4; ++n) {
        int col = h * DHD + n * 16 + lr;
        ctx[(size_t)(b * SEQ + tok) * DM + col] = __float2bfloat16(o[n][r] * inv);
      }
    }
  } else {
    float* base = epart + (size_t)((((b * NH + h) * 2 + e) * 8) + split) * PARTF;
#pragma unroll
    for (int r = 0; r < 4; ++r) {
      int qrow = w * 16 + lks * 4 + r;
#pragma unroll
      for (int n = 0; n < 4; ++n)
        base[qrow * 64 + n * 16 + lr] = o[n][r];
      if (lr == 0) { base[4096 + qrow] = m_r[r]; base[4096 + 64 + qrow] = l_r[r]; }
    }
  }
}

// ----------------------------- edge split-K combine -----------------------------
__global__ __launch_bounds__(256) void k_combine(const float* __restrict__ epart,
                                                 bf16* __restrict__ ctx) {
  const int bid = blockIdx.x;
  const int b = bid / (NH * 2);
  const int rem = bid - b * NH * 2;
  const int h = rem >> 1, e = rem & 1;
  const int tid = threadIdx.x;
  const int row = tid >> 2, cq = tid & 3;
  const float* base0 = epart + (size_t)(((b * NH + h) * 2 + e) * 8) * PARTF;
  float ms[8], ls[8], M = -1e30f;
#pragma unroll
  for (int s = 0; s < 8; ++s) {
    const float* bp = base0 + (size_t)s * PARTF;
    ms[s] = bp[4096 + row];
    ls[s] = bp[4096 + 64 + row];
    M = fmaxf(M, ms[s]);
  }
  float Lt = 0.f, accv[16];
#pragma unroll
  for (int i = 0; i < 16; ++i) accv[i] = 0.f;
#pragma unroll
  for (int s = 0; s < 8; ++s) {
    float wgt = __expf(ms[s] - M);
    Lt += ls[s] * wgt;
    const float* op = base0 + (size_t)s * PARTF + row * 64 + cq * 16;
#pragma unroll
    for (int i = 0; i < 16; ++i) accv[i] += op[i] * wgt;
  }
  float inv = 1.0f / Lt;
  int qblk = e ? NBLK - 1 : 0;
  int tok = qblk * 64 + row;
  bf16* cp = ctx + (size_t)(b * SEQ + tok) * DM + h * DHD + cq * 16;
#pragma unroll
  for (int i = 0; i < 16; ++i) cp[i] = __float2bfloat16(accv[i] * inv);
}

// ----------------------------- classifier: x[:,0,:] @ Wc + bc -----------------------------
__global__ void k_classifier(const bf16* __restrict__ xb, const float* __restrict__ Wc,
                             const float* __restrict__ bc, float* __restrict__ out) {
  const int tid = threadIdx.x, lane = tid & 63, wv = tid >> 6;
  const int b = wv >> 1, c = wv & 1;
  float s = 0.f;
  for (int d = lane; d < DM; d += 64)
    s += __bfloat162float(xb[(size_t)(b * SEQ) * DM + d]) * Wc[d * NCLS + c];
#pragma unroll
  for (int off = 32; off > 0; off >>= 1) s += __shfl_down(s, off);
  if (lane == 0) out[b * NCLS + c] = s + bc[c];
}

// ----------------------------- host launch -----------------------------
extern "C" void kernel_launch(void* const* d_in, const int* in_sizes, int n_in,
                              void* d_out, int out_size, void* d_ws, size_t ws_size,
                              hipStream_t stream) {
  const float* embeddings = (const float*)d_in[0];
  const float* Wp  = (const float*)d_in[2];
  const float* bp  = (const float*)d_in[3];
  const float* pos = (const float*)d_in[4];
  const float* tokv = (const float*)d_in[5];
  const float* lng = (const float*)d_in[6];
  const float* lnb = (const float*)d_in[7];
  const float* Wq  = (const float*)d_in[8];
  const float* bq  = (const float*)d_in[9];
  const float* Wk  = (const float*)d_in[10];
  const float* bk  = (const float*)d_in[11];
  const float* Wv  = (const float*)d_in[12];
  const float* bv  = (const float*)d_in[13];
  const float* Wo  = (const float*)d_in[14];
  const float* bo  = (const float*)d_in[15];
  const float* l1g = (const float*)d_in[16];
  const float* l1b = (const float*)d_in[17];
  const float* W1  = (const float*)d_in[18];
  const float* b1  = (const float*)d_in[19];
  const float* W2  = (const float*)d_in[20];
  const float* b2  = (const float*)d_in[21];
  const float* l2g = (const float*)d_in[22];
  const float* l2b = (const float*)d_in[23];
  const float* Wc  = (const float*)d_in[24];
  const float* bc  = (const float*)d_in[25];
  const int*  bidx = (const int*)d_in[26];
  (void)in_sizes; (void)n_in; (void)out_size; (void)ws_size;

  char* ws = (char*)d_ws;
  size_t off = 0;
  auto alloc = [&](size_t bytes) -> char* {
    char* p = ws + off;
    off += (bytes + 255) & ~(size_t)255;
    return p;
  };
  bf16*  embB  = (bf16*)alloc((size_t)MR * INPD * 2);
  bf16*  wpT   = (bf16*)alloc((size_t)DM * INPD * 2);
  bf16*  wqkvT = (bf16*)alloc((size_t)QKVN * DM * 2);
  bf16*  woT   = (bf16*)alloc((size_t)DM * DM * 2);
  bf16*  w1T   = (bf16*)alloc((size_t)FFD * DM * 2);
  bf16*  w2T   = (bf16*)alloc((size_t)DM * FFD * 2);
  bf16*  xb    = (bf16*)alloc((size_t)MR * DM * 2);   // residual stream (bf16)
  bf16*  gout  = (bf16*)alloc((size_t)MR * DM * 2);   // raw GEMM out (pre-LN)
  bf16*  qkvB  = (bf16*)alloc((size_t)MR * QKVN * 2);
  bf16*  vtB   = (bf16*)alloc((size_t)BATCH * NH * DHD * SEQ * 2);
  bf16*  ctxB  = (bf16*)alloc((size_t)MR * DM * 2);
  bf16*  hB    = (bf16*)alloc((size_t)MR * FFD * 2);
  float* epart = (float*)alloc((size_t)BATCH * NH * 2 * 8 * PARTF * 4);

  // embed: gout = emb @ Wp + bp + pos + tok (bf16); xb = LN(gout)
  k_f32_to_bf16<<<2048, 256, 0, stream>>>(embeddings, embB, MR * INPD);
  k_transpose_one<<<(INPD / 32) * (DM / 32), 256, 0, stream>>>(Wp, wpT, INPD, DM);
  k_gemm<3><<<dim3(DM / 128, MR / 128), 256, 0, stream>>>(embB, wpT, DM, INPD,
      bp, nullptr, nullptr, pos, tokv, gout);
  k_ln_res<false><<<MR / 4, 256, 0, stream>>>(gout, gout, lng, lnb, xb);

  for (int l = 0; l < NL; ++l) {
    k_transpose_layer<<<6912, 256, 0, stream>>>(Wq, Wk, Wv, Wo, W1, W2,
        wqkvT, woT, w1T, w2T, l);
    k_gemm<0><<<dim3(QKVN / 128, MR / 128), 256, 0, stream>>>(xb, wqkvT, QKVN, DM,
        bq + (size_t)l * DM, bk + (size_t)l * DM, bv + (size_t)l * DM,
        nullptr, nullptr, qkvB);
    k_vt<<<dim3(SEQ / 64, BATCH * NH), 256, 0, stream>>>(qkvB, vtB);
    k_attn<<<BATCH * NH * NJOBS, 256, 0, stream>>>(qkvB, vtB, bidx, ctxB, epart);
    k_combine<<<BATCH * NH * 2, 256, 0, stream>>>(epart, ctxB);
    k_gemm<2><<<dim3(DM / 128, MR / 128), 256, 0, stream>>>(ctxB, woT, DM, DM,
        bo + (size_t)l * DM, nullptr, nullptr, nullptr, nullptr, gout);
    k_ln_res<true><<<MR / 4, 256, 0, stream>>>(gout, xb,
        l1g + (size_t)l * DM, l1b + (size_t)l * DM, xb);
    k_gemm<1><<<dim3(FFD / 128, MR / 128), 256, 0, stream>>>(xb, w1T, FFD, DM,
        b1 + (size_t)l * FFD, nullptr, nullptr, nullptr, nullptr, hB);
    k_gemm<2><<<dim3(DM / 128, MR / 128), 256, 0, stream>>>(hB, w2T, DM, FFD,
        b2 + (size_t)l * DM, nullptr, nullptr, nullptr, nullptr, gout);
    k_ln_res<true><<<MR / 4, 256, 0, stream>>>(gout, xb,
        l2g + (size_t)l * DM, l2b + (size_t)l * DM, xb);
  }
  k_classifier<<<1, 256, 0, stream>>>(xb, Wc, bc, (float*)d_out);
}

// Round 8
// 3491.513 us; speedup vs baseline: 1.2573x; 1.0009x over previous
//
#include <hip/hip_runtime.h>
#include <hip/hip_bf16.h>
#include <math.h>

using bf16 = __hip_bfloat16;
typedef short bf16x8 __attribute__((ext_vector_type(8)));
typedef float f32x4 __attribute__((ext_vector_type(4)));
typedef unsigned short u16x4 __attribute__((ext_vector_type(4)));

#define DEV __device__ __forceinline__

constexpr int BATCH = 2, SEQ = 4096, INPD = 1280, DM = 768, FFD = 3072;
constexpr int NL = 12, NH = 12, DHD = 64, NBLK = 64, NCLS = 2;
constexpr int MR = BATCH * SEQ;       // 8192 token rows
constexpr int QKVN = 3 * DM;          // 2304
constexpr int NJOBS = 62 + 16;        // interior blocks + 2 edges * 8 splits
constexpr int PARTF = 64 * 64 + 128;  // floats per edge partial (O + m + l)

DEV void gload_lds16(const void* g, void* l) {
  __builtin_amdgcn_global_load_lds(
      (const __attribute__((address_space(1))) unsigned int*)g,
      (__attribute__((address_space(3))) unsigned int*)l, 16, 0, 0);
}

DEV f32x4 mfma16(bf16x8 a, bf16x8 b, f32x4 c) {
  return __builtin_amdgcn_mfma_f32_16x16x32_bf16(a, b, c, 0, 0, 0);
}

DEV float b2f(unsigned short u) { return __uint_as_float((unsigned)u << 16); }
DEV unsigned short f2b(float x) {
  bf16 h = __float2bfloat16(x);
  return *(unsigned short*)&h;
}

// XCD-chunked bijective block swizzle (m204).
DEV int xcd_swizzle(int orig, int nwg) {
  int q = nwg >> 3, r = nwg & 7;
  int xcd = orig & 7, pos_ = orig >> 3;
  return (xcd < r ? xcd * (q + 1) : r * (q + 1) + (xcd - r) * q) + pos_;
}

// ----------------------------- f32 -> bf16 convert (16B stores) -----------------------------
__global__ void k_f32_to_bf16(const float* __restrict__ in, bf16* __restrict__ out, int n) {
  int i = (blockIdx.x * blockDim.x + threadIdx.x) * 8;
  int stride = gridDim.x * blockDim.x * 8;
  for (; i < n; i += stride) {
    float4 a = *(const float4*)(in + i);
    float4 b = *(const float4*)(in + i + 4);
    bf16 t8[8];
    t8[0] = __float2bfloat16(a.x); t8[1] = __float2bfloat16(a.y);
    t8[2] = __float2bfloat16(a.z); t8[3] = __float2bfloat16(a.w);
    t8[4] = __float2bfloat16(b.x); t8[5] = __float2bfloat16(b.y);
    t8[6] = __float2bfloat16(b.z); t8[7] = __float2bfloat16(b.w);
    *(bf16x8*)(out + i) = *(bf16x8*)t8;
  }
}

// ------------------------- weight transpose (K,N)f32 -> (N,K)bf16 -------------------------
DEV void tr32_tile(const float* __restrict__ src, bf16* __restrict__ dst,
                   int K, int N, int tile, float t[32][33], int tid) {
  int nt = N >> 5;
  int tk = tile / nt, tn = tile - tk * nt;
  int tx = tid & 31, ty = tid >> 5;
#pragma unroll
  for (int i = 0; i < 4; ++i)
    t[ty + 8 * i][tx] = src[(size_t)(tk * 32 + ty + 8 * i) * N + tn * 32 + tx];
  __syncthreads();
#pragma unroll
  for (int i = 0; i < 4; ++i)
    dst[(size_t)(tn * 32 + ty + 8 * i) * K + tk * 32 + tx] = __float2bfloat16(t[tx][ty + 8 * i]);
}

__global__ __launch_bounds__(256) void k_transpose_one(const float* __restrict__ src,
                                                       bf16* __restrict__ dst, int K, int N) {
  __shared__ float t[32][33];
  tr32_tile(src, dst, K, N, blockIdx.x, t, threadIdx.x);
}

__global__ __launch_bounds__(256) void k_transpose_layer(
    const float* __restrict__ Wq, const float* __restrict__ Wk,
    const float* __restrict__ Wv, const float* __restrict__ Wo,
    const float* __restrict__ W1, const float* __restrict__ W2,
    bf16* __restrict__ wqkvT, bf16* __restrict__ woT,
    bf16* __restrict__ w1T, bf16* __restrict__ w2T, int l) {
  __shared__ float t[32][33];
  int id = blockIdx.x;
  const float* src; bf16* dst; int K, N;
  if (id < 1728) {               // Wq,Wk,Wv -> concatenated (2304 x 768)
    int m = id / 576; id -= m * 576;
    src = (m == 0 ? Wq : m == 1 ? Wk : Wv) + (size_t)l * DM * DM;
    dst = wqkvT + (size_t)m * DM * DM; K = DM; N = DM;
  } else if (id < 2304) {
    id -= 1728; src = Wo + (size_t)l * DM * DM; dst = woT; K = DM; N = DM;
  } else if (id < 4608) {
    id -= 2304; src = W1 + (size_t)l * DM * FFD; dst = w1T; K = DM; N = FFD;
  } else {
    id -= 4608; src = W2 + (size_t)l * FFD * DM; dst = w2T; K = FFD; N = DM;
  }
  tr32_tile(src, dst, K, N, id, t, threadIdx.x);
}

// -------------------- 128^2 GEMM (2-phase, proven): C = A * BT^T --------------------
// For narrow-N shapes (O, W2, embed). Epilogues write bf16 raw (res fused in k_ln_res).
// EPI: 2 = +bias ; 3 = +bias +pos +tok (embed)
template <int EPI>
__global__ __launch_bounds__(256) void k_gemm(
    const bf16* __restrict__ A, const bf16* __restrict__ BT, int N, int K,
    const float* __restrict__ b0, const float* __restrict__ pos, const float* __restrict__ tok,
    bf16* __restrict__ Cb) {
  __shared__ __align__(16) bf16 lA[2][128 * 32];
  __shared__ __align__(16) bf16 lB[2][128 * 32];
  const int tid = threadIdx.x;
  const int gx = gridDim.x;
  const int tile = xcd_swizzle(blockIdx.y * gx + blockIdx.x, gx * gridDim.y);
  const int bx = tile % gx, by = tile / gx;
  const int bm = by * 128, bn = bx * 128;
  const int lane = tid & 63, wid = tid >> 6;
  const int wm = (wid >> 1) * 64, wn = (wid & 1) * 64;
  const int lr = lane & 15, lks = lane >> 4;
  const bf16* Abase = A + (size_t)bm * K;
  const bf16* Bbase = BT + (size_t)bn * K;

  auto stage = [&](int buf, int t) {
    int k0 = t << 5;
#pragma unroll
    for (int ss = 0; ss < 2; ++ss) {
      int seg = tid + ss * 256;
      int row = seg >> 2, slot = seg & 3;
      int kseg = slot ^ ((row >> 1) & 3);
      gload_lds16(Abase + (size_t)row * K + k0 + kseg * 8, &lA[buf][seg * 8]);
      gload_lds16(Bbase + (size_t)row * K + k0 + kseg * 8, &lB[buf][seg * 8]);
    }
  };

  f32x4 acc[4][4] = {};
  const int nt = K >> 5;
  stage(0, 0);
  __syncthreads();
  for (int t = 0; t < nt; ++t) {
    const int buf = t & 1;
    if (t + 1 < nt) stage(buf ^ 1, t + 1);
    bf16x8 af[4], bfr[4];
#pragma unroll
    for (int m = 0; m < 4; ++m) {
      int rr = wm + m * 16 + lr;
      af[m] = *(const bf16x8*)(&lA[buf][rr * 32 + ((lks ^ ((rr >> 1) & 3)) << 3)]);
    }
#pragma unroll
    for (int n = 0; n < 4; ++n) {
      int rr = wn + n * 16 + lr;
      bfr[n] = *(const bf16x8*)(&lB[buf][rr * 32 + ((lks ^ ((rr >> 1) & 3)) << 3)]);
    }
#pragma unroll
    for (int m = 0; m < 4; ++m)
#pragma unroll
      for (int n = 0; n < 4; ++n)
        acc[m][n] = mfma16(af[m], bfr[n], acc[m][n]);
    __syncthreads();
  }
  const int gq = lane >> 4;
#pragma unroll
  for (int m = 0; m < 4; ++m) {
#pragma unroll
    for (int n = 0; n < 4; ++n) {
      int gcol = bn + wn + n * 16 + lr;
      f32x4 v = acc[m][n];
#pragma unroll
      for (int rr = 0; rr < 4; ++rr) {
        int grow = bm + wm + m * 16 + gq * 4 + rr;
        float x = v[rr];
        if constexpr (EPI == 2) {
          x += b0[gcol];
        } else {
          x += b0[gcol] + pos[(size_t)(grow & (SEQ - 1)) * N + gcol] + tok[gcol];
        }
        Cb[(size_t)grow * N + gcol] = __float2bfloat16(x);
      }
    }
  }
}

// ------------- 256x128 GEMM (2-phase, 8 waves): wide-N K=768 shapes (QKV, W1) -------------
// BM=256, BN=128, BK=32; wave grid 4M x 2N, per-wave 64x64 (same acc/frag footprint as 128^2).
// Staging: 3 gload_lds16/thread per K-step (25% less than 128^2); LDS 48KB -> 3 blocks/CU.
// EPI: 0 = +segmented-bias(q/k/v) ; 1 = +bias, gelu
template <int EPI>
__global__ __launch_bounds__(512) void k_gemm_big(
    const bf16* __restrict__ A, const bf16* __restrict__ BT, int N, int K,
    const float* __restrict__ b0, const float* __restrict__ b1, const float* __restrict__ b2,
    bf16* __restrict__ Cb) {
  __shared__ __align__(16) bf16 lA[2][256 * 32];
  __shared__ __align__(16) bf16 lB[2][128 * 32];
  const int tid = threadIdx.x;
  const int gx = gridDim.x;
  const int tile = xcd_swizzle(blockIdx.y * gx + blockIdx.x, gx * gridDim.y);
  const int bx = tile % gx, by = tile / gx;
  const int bm = by * 256, bn = bx * 128;
  const int lane = tid & 63, wid = tid >> 6;
  const int wm = (wid >> 1) * 64, wn = (wid & 1) * 64;  // 4M x 2N waves
  const int lr = lane & 15, lks = lane >> 4;
  const bf16* Abase = A + (size_t)bm * K;
  const bf16* Bbase = BT + (size_t)bn * K;

  // A: 1024 segs (256 rows x 4 slots) = 2/thread; B: 512 segs = 1/thread.
  auto stage = [&](int buf, int t) {
    int k0 = t << 5;
#pragma unroll
    for (int ss = 0; ss < 2; ++ss) {
      int seg = tid + ss * 512;
      int row = seg >> 2, slot = seg & 3;
      int kseg = slot ^ ((row >> 1) & 3);
      gload_lds16(Abase + (size_t)row * K + k0 + kseg * 8, &lA[buf][seg * 8]);
    }
    {
      int row = tid >> 2, slot = tid & 3;
      int kseg = slot ^ ((row >> 1) & 3);
      gload_lds16(Bbase + (size_t)row * K + k0 + kseg * 8, &lB[buf][tid * 8]);
    }
  };

  f32x4 acc[4][4] = {};
  const int nt = K >> 5;
  stage(0, 0);
  __syncthreads();
  for (int t = 0; t < nt; ++t) {
    const int buf = t & 1;
    if (t + 1 < nt) stage(buf ^ 1, t + 1);
    bf16x8 af[4], bfr[4];
#pragma unroll
    for (int m = 0; m < 4; ++m) {
      int rr = wm + m * 16 + lr;
      af[m] = *(const bf16x8*)(&lA[buf][rr * 32 + ((lks ^ ((rr >> 1) & 3)) << 3)]);
    }
#pragma unroll
    for (int n = 0; n < 4; ++n) {
      int rr = wn + n * 16 + lr;
      bfr[n] = *(const bf16x8*)(&lB[buf][rr * 32 + ((lks ^ ((rr >> 1) & 3)) << 3)]);
    }
#pragma unroll
    for (int m = 0; m < 4; ++m)
#pragma unroll
      for (int n = 0; n < 4; ++n)
        acc[m][n] = mfma16(af[m], bfr[n], acc[m][n]);
    __syncthreads();
  }
  const int gq = lane >> 4;
#pragma unroll
  for (int m = 0; m < 4; ++m) {
#pragma unroll
    for (int n = 0; n < 4; ++n) {
      int gcol = bn + wn + n * 16 + lr;
      f32x4 v = acc[m][n];
#pragma unroll
      for (int rr = 0; rr < 4; ++rr) {
        int grow = bm + wm + m * 16 + gq * 4 + rr;
        float x = v[rr];
        if constexpr (EPI == 0) {
          int c = gcol; const float* bb = b0;
          if (c >= 2 * DM) { bb = b2; c -= 2 * DM; }
          else if (c >= DM) { bb = b1; c -= DM; }
          x += bb[c];
        } else {
          x += b0[gcol];
          x = 0.5f * x * (1.0f + erff(x * 0.70710678118654752f));
        }
        Cb[(size_t)grow * N + gcol] = __float2bfloat16(x);
      }
    }
  }
}

// ------- fused residual-add + LayerNorm, all-bf16 streams, wave-per-row, in-place safe -------
template <bool HASRES>
__global__ __launch_bounds__(256) void k_ln_res(
    const bf16* __restrict__ gout, const bf16* res,
    const float* __restrict__ g, const float* __restrict__ b,
    bf16* out) {
  const int wv = threadIdx.x >> 6, lane = threadIdx.x & 63;
  const int row = blockIdx.x * 4 + wv;
  const unsigned short* gp = (const unsigned short*)gout + (size_t)row * DM;
  const unsigned short* rp = (const unsigned short*)res + (size_t)row * DM;
  float v[12];
  float s = 0.f, s2 = 0.f;
#pragma unroll
  for (int i = 0; i < 3; ++i) {
    const int c = i * 256 + lane * 4;
    u16x4 a4 = *(const u16x4*)(gp + c);
    u16x4 r4;
    if constexpr (HASRES) r4 = *(const u16x4*)(rp + c);
#pragma unroll
    for (int k2 = 0; k2 < 4; ++k2) {
      float x = b2f(a4[k2]);
      if constexpr (HASRES) x += b2f(r4[k2]);
      v[i * 4 + k2] = x;
      s += x; s2 += x * x;
    }
  }
#pragma unroll
  for (int off = 1; off < 64; off <<= 1) {
    s += __shfl_xor(s, off);
    s2 += __shfl_xor(s2, off);
  }
  const float mean = s * (1.0f / DM);
  const float var = s2 * (1.0f / DM) - mean * mean;
  const float rs = rsqrtf(var + 1e-12f);
  unsigned short* op = (unsigned short*)out + (size_t)row * DM;
#pragma unroll
  for (int i = 0; i < 3; ++i) {
    const int c = i * 256 + lane * 4;
    float4 g4 = *(const float4*)(g + c);
    float4 b4 = *(const float4*)(b + c);
    u16x4 o4;
    o4[0] = f2b((v[i * 4 + 0] - mean) * rs * g4.x + b4.x);
    o4[1] = f2b((v[i * 4 + 1] - mean) * rs * g4.y + b4.y);
    o4[2] = f2b((v[i * 4 + 2] - mean) * rs * g4.z + b4.z);
    o4[3] = f2b((v[i * 4 + 3] - mean) * rs * g4.w + b4.w);
    *(u16x4*)(op + c) = o4;
  }
}

// ------------------- V transpose: qkv v-section (B,S,H,DH) -> vt (B,H,DH,S) -------------------
__global__ __launch_bounds__(256) void k_vt(const bf16* __restrict__ qkv, bf16* __restrict__ vt) {
  __shared__ unsigned short t[64][72];
  const int bh = blockIdx.y, t0 = blockIdx.x * 64;
  const int b = bh / NH, h = bh - b * NH;
  const int tid = threadIdx.x;
  const int rr = tid >> 2, cs = (tid & 3) * 16;
  const unsigned short* src = (const unsigned short*)qkv +
      (size_t)(b * SEQ + t0 + rr) * QKVN + 2 * DM + h * DHD + cs;
#pragma unroll
  for (int i = 0; i < 16; ++i) t[cs + i][rr] = src[i];
  __syncthreads();
  unsigned short* dst = (unsigned short*)vt + (size_t)(bh * DHD + rr) * SEQ + t0 + cs;
#pragma unroll
  for (int i = 0; i < 16; ++i) dst[i] = t[rr][cs + i];
}

// ----------------------------- block-sparse attention -----------------------------
__global__ __launch_bounds__(256) void k_attn(
    const bf16* __restrict__ qkv, const bf16* __restrict__ vt,
    const int* __restrict__ blk_idx,
    bf16* __restrict__ ctx, float* __restrict__ epart) {
  __shared__ __align__(16) bf16 sQ[64 * 64];
  __shared__ __align__(16) bf16 sK[2][64 * 64];
  __shared__ __align__(16) bf16 sV[2][64 * 64];
  __shared__ __align__(16) bf16 sP[4][16 * 64];
  const int job = blockIdx.x;
  const int b = job / (NH * NJOBS);
  const int rem = job - b * NH * NJOBS;
  const int h = rem / NJOBS;
  const int j = rem - h * NJOBS;
  const int tid = threadIdx.x, lane = tid & 63, w = tid >> 6;
  const int lr = lane & 15, lks = lane >> 4;

  const bool interior = (j < 62);
  int qblk, e = 0, split = 0;
  if (interior) qblk = j + 1;
  else { int tt = j - 62; e = tt >> 3; split = tt & 7; qblk = e ? NBLK - 1 : 0; }
  const int qt0 = qblk * 64;

  const int skip_pos = interior ? (j == 0 ? 2 : (j == 61 ? 4 : 8)) : 8;
  const int nkb = (skip_pos < 8) ? 7 : 8;
  auto kbi_of = [&](int i) {
    int kb = i + (i >= skip_pos ? 1 : 0);
    return interior ? blk_idx[j * 8 + kb] : split * 8 + kb;
  };

  const bf16* kbase0 = qkv + (size_t)b * SEQ * QKVN + DM + h * DHD;
  const bf16* vbase0 = vt + (size_t)((b * NH + h) * DHD) * SEQ;
  auto stageKV = [&](int buf, int kbi) {
    const int kt0 = kbi * 64;
#pragma unroll
    for (int ss = 0; ss < 2; ++ss) {
      int seg = tid + ss * 256;
      int row = seg >> 3, slot = seg & 7;
      int kseg = slot ^ (row & 7);
      gload_lds16(kbase0 + (size_t)(kt0 + row) * QKVN + kseg * 8, &sK[buf][seg * 8]);
      gload_lds16(vbase0 + (size_t)row * SEQ + kt0 + kseg * 8, &sV[buf][seg * 8]);
    }
  };

  {
    const bf16* qbase = qkv + (size_t)(b * SEQ + qt0) * QKVN + h * DHD;
#pragma unroll
    for (int ss = 0; ss < 2; ++ss) {
      int seg = tid + ss * 256;
      int row = seg >> 3, slot = seg & 7;
      int kseg = slot ^ (row & 7);
      gload_lds16(qbase + (size_t)row * QKVN + kseg * 8, sQ + seg * 8);
    }
  }
  stageKV(0, kbi_of(0));
  __syncthreads();
  bf16x8 aq[2];
#pragma unroll
  for (int kk = 0; kk < 2; ++kk) {
    int rq = w * 16 + lr;
    int slot = (kk * 4 + lks) ^ (rq & 7);
    aq[kk] = *(const bf16x8*)(sQ + rq * 64 + slot * 8);
  }

  float m_r[4], l_r[4];
  f32x4 o[4] = {};
#pragma unroll
  for (int r = 0; r < 4; ++r) { m_r[r] = -1e30f; l_r[r] = 0.f; }

  for (int i = 0; i < nkb; ++i) {
    const int buf = i & 1;
    if (i + 1 < nkb) stageKV(buf ^ 1, kbi_of(i + 1));
    f32x4 sfr[4];
#pragma unroll
    for (int n = 0; n < 4; ++n) {
      f32x4 z = {};
#pragma unroll
      for (int kk = 0; kk < 2; ++kk) {
        int rk = n * 16 + lr;
        int slot = (kk * 4 + lks) ^ (rk & 7);
        bf16x8 kf = *(const bf16x8*)(&sK[buf][rk * 64 + slot * 8]);
        z = mfma16(aq[kk], kf, z);
      }
      sfr[n] = z;
    }
#pragma unroll
    for (int n = 0; n < 4; ++n)
#pragma unroll
      for (int r = 0; r < 4; ++r) sfr[n][r] *= 0.125f;
    float alpha[4];
#pragma unroll
    for (int r = 0; r < 4; ++r) {
      float tmx = fmaxf(fmaxf(sfr[0][r], sfr[1][r]), fmaxf(sfr[2][r], sfr[3][r]));
#pragma unroll
      for (int off = 1; off < 16; off <<= 1) tmx = fmaxf(tmx, __shfl_xor(tmx, off));
      float mnew = fmaxf(m_r[r], tmx);
      alpha[r] = __expf(m_r[r] - mnew);
      m_r[r] = mnew;
    }
#pragma unroll
    for (int r = 0; r < 4; ++r) {
      float su = 0.f;
#pragma unroll
      for (int n = 0; n < 4; ++n) {
        float p = __expf(sfr[n][r] - m_r[r]);
        sfr[n][r] = p;
        su += p;
      }
#pragma unroll
      for (int off = 1; off < 16; off <<= 1) su += __shfl_xor(su, off);
      l_r[r] = l_r[r] * alpha[r] + su;
    }
#pragma unroll
    for (int n = 0; n < 4; ++n) {
#pragma unroll
      for (int r = 0; r < 4; ++r) {
        int prow = lks * 4 + r;
        int col = n * 16 + lr;
        int eo = prow * 64 + ((((col >> 3) ^ (prow & 7)) << 3) | (col & 7));
        sP[w][eo] = __float2bfloat16(sfr[n][r]);
      }
    }
#pragma unroll
    for (int n = 0; n < 4; ++n)
#pragma unroll
      for (int r = 0; r < 4; ++r) o[n][r] *= alpha[r];
    asm volatile("s_waitcnt lgkmcnt(0)" ::: "memory");
    __builtin_amdgcn_sched_barrier(0);
    bf16x8 pa[2];
#pragma unroll
    for (int kk = 0; kk < 2; ++kk) {
      int slot = (kk * 4 + lks) ^ (lr & 7);
      pa[kk] = *(const bf16x8*)(sP[w] + lr * 64 + slot * 8);
    }
#pragma unroll
    for (int n = 0; n < 4; ++n) {
#pragma unroll
      for (int kk = 0; kk < 2; ++kk) {
        int rv = n * 16 + lr;
        int slot = (kk * 4 + lks) ^ (rv & 7);
        bf16x8 vf = *(const bf16x8*)(&sV[buf][rv * 64 + slot * 8]);
        o[n] = mfma16(pa[kk], vf, o[n]);
      }
    }
    __syncthreads();
  }
  if (interior) {
#pragma unroll
    for (int r = 0; r < 4; ++r) {
      float inv = 1.0f / l_r[r];
      int tok = qt0 + w * 16 + lks * 4 + r;
#pragma unroll
      for (int n = 0; n < 4; ++n) {
        int col = h * DHD + n * 16 + lr;
        ctx[(size_t)(b * SEQ + tok) * DM + col] = __float2bfloat16(o[n][r] * inv);
      }
    }
  } else {
    float* base = epart + (size_t)((((b * NH + h) * 2 + e) * 8) + split) * PARTF;
#pragma unroll
    for (int r = 0; r < 4; ++r) {
      int qrow = w * 16 + lks * 4 + r;
#pragma unroll
      for (int n = 0; n < 4; ++n)
        base[qrow * 64 + n * 16 + lr] = o[n][r];
      if (lr == 0) { base[4096 + qrow] = m_r[r]; base[4096 + 64 + qrow] = l_r[r]; }
    }
  }
}

// ----------------------------- edge split-K combine -----------------------------
__global__ __launch_bounds__(256) void k_combine(const float* __restrict__ epart,
                                                 bf16* __restrict__ ctx) {
  const int bid = blockIdx.x;
  const int b = bid / (NH * 2);
  const int rem = bid - b * NH * 2;
  const int h = rem >> 1, e = rem & 1;
  const int tid = threadIdx.x;
  const int row = tid >> 2, cq = tid & 3;
  const float* base0 = epart + (size_t)(((b * NH + h) * 2 + e) * 8) * PARTF;
  float ms[8], ls[8], M = -1e30f;
#pragma unroll
  for (int s = 0; s < 8; ++s) {
    const float* bp = base0 + (size_t)s * PARTF;
    ms[s] = bp[4096 + row];
    ls[s] = bp[4096 + 64 + row];
    M = fmaxf(M, ms[s]);
  }
  float Lt = 0.f, accv[16];
#pragma unroll
  for (int i = 0; i < 16; ++i) accv[i] = 0.f;
#pragma unroll
  for (int s = 0; s < 8; ++s) {
    float wgt = __expf(ms[s] - M);
    Lt += ls[s] * wgt;
    const float* op = base0 + (size_t)s * PARTF + row * 64 + cq * 16;
#pragma unroll
    for (int i = 0; i < 16; ++i) accv[i] += op[i] * wgt;
  }
  float inv = 1.0f / Lt;
  int qblk = e ? NBLK - 1 : 0;
  int tok = qblk * 64 + row;
  bf16* cp = ctx + (size_t)(b * SEQ + tok) * DM + h * DHD + cq * 16;
#pragma unroll
  for (int i = 0; i < 16; ++i) cp[i] = __float2bfloat16(accv[i] * inv);
}

// ----------------------------- classifier: x[:,0,:] @ Wc + bc -----------------------------
__global__ void k_classifier(const bf16* __restrict__ xb, const float* __restrict__ Wc,
                             const float* __restrict__ bc, float* __restrict__ out) {
  const int tid = threadIdx.x, lane = tid & 63, wv = tid >> 6;
  const int b = wv >> 1, c = wv & 1;
  float s = 0.f;
  for (int d = lane; d < DM; d += 64)
    s += __bfloat162float(xb[(size_t)(b * SEQ) * DM + d]) * Wc[d * NCLS + c];
#pragma unroll
  for (int off = 32; off > 0; off >>= 1) s += __shfl_down(s, off);
  if (lane == 0) out[b * NCLS + c] = s + bc[c];
}

// ----------------------------- host launch -----------------------------
extern "C" void kernel_launch(void* const* d_in, const int* in_sizes, int n_in,
                              void* d_out, int out_size, void* d_ws, size_t ws_size,
                              hipStream_t stream) {
  const float* embeddings = (const float*)d_in[0];
  const float* Wp  = (const float*)d_in[2];
  const float* bp  = (const float*)d_in[3];
  const float* pos = (const float*)d_in[4];
  const float* tokv = (const float*)d_in[5];
  const float* lng = (const float*)d_in[6];
  const float* lnb = (const float*)d_in[7];
  const float* Wq  = (const float*)d_in[8];
  const float* bq  = (const float*)d_in[9];
  const float* Wk  = (const float*)d_in[10];
  const float* bk  = (const float*)d_in[11];
  const float* Wv  = (const float*)d_in[12];
  const float* bv  = (const float*)d_in[13];
  const float* Wo  = (const float*)d_in[14];
  const float* bo  = (const float*)d_in[15];
  const float* l1g = (const float*)d_in[16];
  const float* l1b = (const float*)d_in[17];
  const float* W1  = (const float*)d_in[18];
  const float* b1  = (const float*)d_in[19];
  const float* W2  = (const float*)d_in[20];
  const float* b2  = (const float*)d_in[21];
  const float* l2g = (const float*)d_in[22];
  const float* l2b = (const float*)d_in[23];
  const float* Wc  = (const float*)d_in[24];
  const float* bc  = (const float*)d_in[25];
  const int*  bidx = (const int*)d_in[26];
  (void)in_sizes; (void)n_in; (void)out_size; (void)ws_size;

  char* ws = (char*)d_ws;
  size_t off = 0;
  auto alloc = [&](size_t bytes) -> char* {
    char* p = ws + off;
    off += (bytes + 255) & ~(size_t)255;
    return p;
  };
  bf16*  embB  = (bf16*)alloc((size_t)MR * INPD * 2);
  bf16*  wpT   = (bf16*)alloc((size_t)DM * INPD * 2);
  bf16*  wqkvT = (bf16*)alloc((size_t)QKVN * DM * 2);
  bf16*  woT   = (bf16*)alloc((size_t)DM * DM * 2);
  bf16*  w1T   = (bf16*)alloc((size_t)FFD * DM * 2);
  bf16*  w2T   = (bf16*)alloc((size_t)DM * FFD * 2);
  bf16*  xb    = (bf16*)alloc((size_t)MR * DM * 2);   // residual stream (bf16)
  bf16*  gout  = (bf16*)alloc((size_t)MR * DM * 2);   // raw GEMM out (pre-LN)
  bf16*  qkvB  = (bf16*)alloc((size_t)MR * QKVN * 2);
  bf16*  vtB   = (bf16*)alloc((size_t)BATCH * NH * DHD * SEQ * 2);
  bf16*  ctxB  = (bf16*)alloc((size_t)MR * DM * 2);
  bf16*  hB    = (bf16*)alloc((size_t)MR * FFD * 2);
  float* epart = (float*)alloc((size_t)BATCH * NH * 2 * 8 * PARTF * 4);

  // embed: gout = emb @ Wp + bp + pos + tok (bf16); xb = LN(gout)
  k_f32_to_bf16<<<2048, 256, 0, stream>>>(embeddings, embB, MR * INPD);
  k_transpose_one<<<(INPD / 32) * (DM / 32), 256, 0, stream>>>(Wp, wpT, INPD, DM);
  k_gemm<3><<<dim3(DM / 128, MR / 128), 256, 0, stream>>>(embB, wpT, DM, INPD,
      bp, pos, tokv, gout);
  k_ln_res<false><<<MR / 4, 256, 0, stream>>>(gout, gout, lng, lnb, xb);

  for (int l = 0; l < NL; ++l) {
    k_transpose_layer<<<6912, 256, 0, stream>>>(Wq, Wk, Wv, Wo, W1, W2,
        wqkvT, woT, w1T, w2T, l);
    k_gemm_big<0><<<dim3(QKVN / 128, MR / 256), 512, 0, stream>>>(xb, wqkvT, QKVN, DM,
        bq + (size_t)l * DM, bk + (size_t)l * DM, bv + (size_t)l * DM, qkvB);
    k_vt<<<dim3(SEQ / 64, BATCH * NH), 256, 0, stream>>>(qkvB, vtB);
    k_attn<<<BATCH * NH * NJOBS, 256, 0, stream>>>(qkvB, vtB, bidx, ctxB, epart);
    k_combine<<<BATCH * NH * 2, 256, 0, stream>>>(epart, ctxB);
    k_gemm<2><<<dim3(DM / 128, MR / 128), 256, 0, stream>>>(ctxB, woT, DM, DM,
        bo + (size_t)l * DM, nullptr, nullptr, gout);
    k_ln_res<true><<<MR / 4, 256, 0, stream>>>(gout, xb,
        l1g + (size_t)l * DM, l1b + (size_t)l * DM, xb);
    k_gemm_big<1><<<dim3(FFD / 128, MR / 256), 512, 0, stream>>>(xb, w1T, FFD, DM,
        b1 + (size_t)l * FFD, nullptr, nullptr, hB);
    k_gemm<2><<<dim3(DM / 128, MR / 128), 256, 0, stream>>>(hB, w2T, DM, FFD,
        b2 + (size_t)l * DM, nullptr, nullptr, gout);
    k_ln_res<true><<<MR / 4, 256, 0, stream>>>(gout, xb,
        l2g + (size_t)l * DM, l2b + (size_t)l * DM, xb);
  }
  k_classifier<<<1, 256, 0, stream>>>(xb, Wc, bc, (float*)d_out);
}